// Round 3
// baseline (1351.056 us; speedup 1.0000x reference)
//
#include <hip/hip_runtime.h>
#include <cstdint>
#include <cmath>

#define D 128
#define SCAN_BS 1024

// ---------------------------------------------------------------- mask canon
__global__ void mask_canon_kernel(const unsigned char* __restrict__ mraw,
                                  int* __restrict__ mout, int n) {
    int i = blockIdx.x * blockDim.x + threadIdx.x;
    if (i >= n) return;
    bool isbool = (mraw[1] | mraw[2] | mraw[3]) != 0;
    int v;
    if (isbool) v = (mraw[i] != 0);
    else        v = (((const int*)mraw)[i] != 0);
    mout[i] = v;
}

// ---------------------------------------------------------------- node norms
__global__ void norm_kernel(const float* __restrict__ x, float* __restrict__ nrm, int n) {
    int t = blockIdx.x * blockDim.x + threadIdx.x;
    int i = t >> 4, lane = t & 15;
    if (i >= n) return;
    const float4* xr = (const float4*)(x + (size_t)i * D);
    float4 a = xr[lane * 2], b = xr[lane * 2 + 1];
    float acc = a.x*a.x + a.y*a.y + a.z*a.z + a.w*a.w
              + b.x*b.x + b.y*b.y + b.z*b.z + b.w*b.w;
    #pragma unroll
    for (int o = 8; o; o >>= 1) acc += __shfl_xor(acc, o, 16);
    if (lane == 0) nrm[i] = fmaxf(sqrtf(acc), 1e-8f);
}

// ---------------------------------------------------------------- edge cos
// writes (attr?attr[e]:1)*cos to out[pos?pos[e]:e]
__global__ void edge_cos_kernel(const float* __restrict__ x,
                                const int* __restrict__ src,
                                const int* __restrict__ dst,
                                const float* __restrict__ attr,
                                const float* __restrict__ nrm,
                                const int* __restrict__ pos,
                                float* __restrict__ out, int e_total) {
    int t = blockIdx.x * blockDim.x + threadIdx.x;
    int e = t >> 4, lane = t & 15;
    if (e >= e_total) return;
    int s = src[e], d = dst[e];
    const float4* xs = (const float4*)(x + (size_t)s * D);
    const float4* xd = (const float4*)(x + (size_t)d * D);
    float acc = 0.f;
    #pragma unroll
    for (int q = 0; q < 2; q++) {
        float4 a = xs[lane * 2 + q];
        float4 b = xd[lane * 2 + q];
        acc += a.x*b.x + a.y*b.y + a.z*b.z + a.w*b.w;
    }
    #pragma unroll
    for (int o = 8; o; o >>= 1) acc += __shfl_xor(acc, o, 16);
    if (lane == 0) {
        float c = acc / (nrm[s] * nrm[d]);
        out[pos ? pos[e] : e] = attr ? attr[e] * c : c;
    }
}

// permute a per-edge array into sorted order: dst[pos[e]] = src[e]
__global__ void permute_kernel(const float* __restrict__ a, const int* __restrict__ pos,
                               float* __restrict__ out, int e_total) {
    int e = blockIdx.x * blockDim.x + threadIdx.x;
    if (e < e_total) out[pos[e]] = a[e];
}

// ---------------------------------------------------------------- counting sort
__global__ void hist_kernel(const int* __restrict__ dst, int* __restrict__ deg, int e_total) {
    int e = blockIdx.x * blockDim.x + threadIdx.x;
    if (e < e_total) atomicAdd(&deg[dst[e]], 1);
}

__global__ __launch_bounds__(SCAN_BS)
void scan_block_kernel(const int* __restrict__ deg, int* __restrict__ off,
                       int* __restrict__ bsum, int n) {
    __shared__ int s[SCAN_BS];
    int gid = blockIdx.x * SCAN_BS + threadIdx.x;
    int v = (gid < n) ? deg[gid] : 0;
    s[threadIdx.x] = v;
    __syncthreads();
    for (int o = 1; o < SCAN_BS; o <<= 1) {
        int t = (threadIdx.x >= o) ? s[threadIdx.x - o] : 0;
        __syncthreads();
        s[threadIdx.x] += t;
        __syncthreads();
    }
    if (gid < n) off[gid] = s[threadIdx.x] - v;
    if (threadIdx.x == SCAN_BS - 1) bsum[blockIdx.x] = s[SCAN_BS - 1];
}

__global__ void scan_bsum_kernel(int* __restrict__ bsum, int nb) {
    __shared__ int s[256];
    int v = (threadIdx.x < nb) ? bsum[threadIdx.x] : 0;
    s[threadIdx.x] = v;
    __syncthreads();
    for (int o = 1; o < 256; o <<= 1) {
        int t = (threadIdx.x >= o) ? s[threadIdx.x - o] : 0;
        __syncthreads();
        s[threadIdx.x] += t;
        __syncthreads();
    }
    if (threadIdx.x < nb) bsum[threadIdx.x] = s[threadIdx.x] - v;
}

__global__ __launch_bounds__(SCAN_BS)
void add_offsets_kernel(int* __restrict__ off, const int* __restrict__ bsum,
                        int* __restrict__ tmp, int n, int e_total) {
    int gid = blockIdx.x * SCAN_BS + threadIdx.x;
    if (gid < n) {
        off[gid] += bsum[blockIdx.x];
        tmp[gid] = 0;
    }
    if (gid == 0) off[n] = e_total;
}

__global__ void sort_scatter_kernel(const int* __restrict__ src, const int* __restrict__ dst,
                                    const int* __restrict__ off, int* __restrict__ tmp,
                                    int* __restrict__ ssrc, int* __restrict__ pos, int e_total) {
    int e = blockIdx.x * blockDim.x + threadIdx.x;
    if (e >= e_total) return;
    int d = dst[e];
    int p = off[d] + atomicAdd(&tmp[d], 1);
    ssrc[p] = src[e];
    pos[e] = p;
}

// ---------------------------------------------------------------- masked GEMM
// h[i][j] = mask[i] ? sum_k x[i][k]*W[j][k] : x[i][j]
// One thread per row. x row in VGPRs; W read via wave-uniform indices ->
// scalar loads (SGPR broadcast operands). No LDS, no barriers.
__global__ __launch_bounds__(256)
void gemm_rowreg_kernel(const float* __restrict__ x, const float* __restrict__ W,
                        const int* __restrict__ mask, float* __restrict__ h, int n) {
    int i = blockIdx.x * blockDim.x + threadIdx.x;
    if (i >= n) return;
    const float4* xp = (const float4*)(x + (size_t)i * D);
    float4 xr[32];
    #pragma unroll
    for (int q = 0; q < 32; q++) xr[q] = xp[q];
    float4* hp = (float4*)(h + (size_t)i * D);
    bool m = mask ? (mask[i] != 0) : true;
    if (!m) {   // pass-through rows are contiguous (i >= 0.8N) -> wave-uniform
        #pragma unroll
        for (int q = 0; q < 32; q++) hp[q] = xr[q];
        return;
    }
    const float4* Wf = (const float4*)W;   // Wf[j*32 + q] = W[j][4q..4q+3]
    for (int j0 = 0; j0 < D; j0 += 4) {    // j0 scalar -> W addresses uniform
        float a0 = 0.f, a1 = 0.f, a2 = 0.f, a3 = 0.f;
        #pragma unroll
        for (int q = 0; q < 32; q++) {
            float4 xv = xr[q];
            float4 w0 = Wf[(j0 + 0) * 32 + q];
            float4 w1 = Wf[(j0 + 1) * 32 + q];
            float4 w2 = Wf[(j0 + 2) * 32 + q];
            float4 w3 = Wf[(j0 + 3) * 32 + q];
            a0 += xv.x*w0.x + xv.y*w0.y + xv.z*w0.z + xv.w*w0.w;
            a1 += xv.x*w1.x + xv.y*w1.y + xv.z*w1.z + xv.w*w1.w;
            a2 += xv.x*w2.x + xv.y*w2.y + xv.z*w2.z + xv.w*w2.w;
            a3 += xv.x*w3.x + xv.y*w3.y + xv.z*w3.z + xv.w*w3.w;
        }
        hp[j0 >> 2] = make_float4(a0, a1, a2, a3);
    }
}

// ---------------------------------------------------------------- aggregate
// One 64-lane wave per node; ea_s already in sorted order.
__global__ __launch_bounds__(256)
void aggregate_kernel(const float* __restrict__ h,
                      const int* __restrict__ ssrc, const float* __restrict__ ea_s,
                      const int* __restrict__ off,
                      const float* __restrict__ bias, const int* __restrict__ mask,
                      float* __restrict__ out, int n) {
    int t = blockIdx.x * blockDim.x + threadIdx.x;
    int i = t >> 6, lane = t & 63;
    if (i >= n) return;
    float2 hv = ((const float2*)(h + (size_t)i * D))[lane];
    float2* op = (float2*)(out + (size_t)i * D) + lane;
    bool m = mask ? (mask[i] != 0) : true;
    if (!m) { *op = hv; return; }
    int s0 = off[i], s1 = off[i + 1];
    float a0 = 0.f, a1 = 0.f;
    for (int p = s0; p < s1; p++) {
        int s = ssrc[p];
        float a = ea_s[p];
        float2 v = ((const float2*)(h + (size_t)s * D))[lane];
        a0 += a * v.x; a1 += a * v.y;
    }
    float inv = 1.0f / fmaxf((float)(s1 - s0), 1.0f);
    float2 b2 = ((const float2*)bias)[lane];
    float z0 = a0 * inv + hv.x + b2.x;
    float z1 = a1 * inv + hv.y + b2.y;
    float2 o;
    o.x = 1.0f / (1.0f + expf(-z0));
    o.y = 1.0f / (1.0f + expf(-z1));
    *op = o;
}

// ---------------------------------------------------------------- host side
static void build_sorted(const int* src, const int* dst, int* off, int* tmp, int* bsum,
                         int* ssrc, int* pos, int n, int e, hipStream_t stream) {
    int nb = (n + SCAN_BS - 1) / SCAN_BS;
    hipMemsetAsync(tmp, 0, (size_t)n * sizeof(int), stream);
    hist_kernel<<<(e + 255) / 256, 256, 0, stream>>>(dst, tmp, e);
    scan_block_kernel<<<nb, SCAN_BS, 0, stream>>>(tmp, off, bsum, n);
    scan_bsum_kernel<<<1, 256, 0, stream>>>(bsum, nb);
    add_offsets_kernel<<<nb, SCAN_BS, 0, stream>>>(off, bsum, tmp, n, e);
    sort_scatter_kernel<<<(e + 255) / 256, 256, 0, stream>>>(src, dst, off, tmp, ssrc, pos, e);
}

static void run_layer(const float* xin, const float* W, const float* b, const int* mask,
                      const int* ssrc, const float* ea_s, const int* off,
                      float* h, float* outp, int n, int e, hipStream_t stream) {
    gemm_rowreg_kernel<<<(n + 255) / 256, 256, 0, stream>>>(xin, W, mask, h, n);
    aggregate_kernel<<<((size_t)n * 64 + 255) / 256, 256, 0, stream>>>(
        h, ssrc, ea_s, off, b, mask, outp, n);
}

extern "C" void kernel_launch(void* const* d_in, const int* in_sizes, int n_in,
                              void* d_out, int out_size, void* d_ws, size_t ws_size,
                              hipStream_t stream) {
    const float* x        = (const float*)d_in[0];
    const float* attr_ii  = (const float*)d_in[1];
    const float* attr_uiu = (const float*)d_in[2];
    const float* W1       = (const float*)d_in[3];
    const float* b1       = (const float*)d_in[4];
    const float* W2       = (const float*)d_in[5];
    const float* b2       = (const float*)d_in[6];
    const float* Wu       = (const float*)d_in[7];
    const float* bu       = (const float*)d_in[8];
    const int*   ei_ii    = (const int*)d_in[9];
    const int*   ei_uiu   = (const int*)d_in[10];
    const unsigned char* mraw = (const unsigned char*)d_in[11];

    const int n = in_sizes[0] / D;      // 100000
    const int e = in_sizes[1];          // 600000
    const size_t ND = (size_t)n * D;

    float* P      = (float*)d_ws;       // node features (updated in place)
    float* A      = P + ND;             // h scratch
    float* ea     = A + ND;             // e (sorted order)
    float* ea_uiu = ea + e;             // e (attr_uiu in sorted order)
    float* nrm    = ea_uiu + e;         // n
    int* maskI    = (int*)(nrm + n);    // n
    int* tmpA     = maskI + n;          // n
    int* bsum     = tmpA + n;           // 256
    int* off_ii   = bsum + 256;         // n+1
    int* off_uiu  = off_ii + (n + 1);   // n+1
    int* ssrc_ii  = off_uiu + (n + 1);  // e
    int* ssrc_uiu = ssrc_ii + e;        // e
    int* pos_ii   = ssrc_uiu + e;       // e
    int* pos_uiu  = pos_ii + e;         // e

    const int* src_ii  = ei_ii,  * dst_ii  = ei_ii + e;
    const int* src_uiu = ei_uiu, * dst_uiu = ei_uiu + e;
    float* out = (float*)d_out;

    mask_canon_kernel<<<(n + 255) / 256, 256, 0, stream>>>(mraw, maskI, n);

    build_sorted(src_ii,  dst_ii,  off_ii,  tmpA, bsum, ssrc_ii,  pos_ii,  n, e, stream);
    build_sorted(src_uiu, dst_uiu, off_uiu, tmpA, bsum, ssrc_uiu, pos_uiu, n, e, stream);
    permute_kernel<<<(e + 255) / 256, 256, 0, stream>>>(attr_uiu, pos_uiu, ea_uiu, e);

    // ea1 (sorted) = attr_ii * cos(x[src], x[dst])
    norm_kernel<<<((size_t)n * 16 + 255) / 256, 256, 0, stream>>>(x, nrm, n);
    edge_cos_kernel<<<((size_t)e * 16 + 255) / 256, 256, 0, stream>>>(x, src_ii, dst_ii, attr_ii, nrm, pos_ii, ea, e);

    // x1 = cgat(x, ii, ea1, mask, W1, b1) -> P
    run_layer(x, W1, b1, maskI, ssrc_ii, ea, off_ii, A, P, n, e, stream);

    // ea2 (sorted) = attr_ii * cos(x1[src], x1[dst])
    norm_kernel<<<((size_t)n * 16 + 255) / 256, 256, 0, stream>>>(P, nrm, n);
    edge_cos_kernel<<<((size_t)e * 16 + 255) / 256, 256, 0, stream>>>(P, src_ii, dst_ii, attr_ii, nrm, pos_ii, ea, e);

    // x2 = cgat(x1, ii, ea2, mask, W2, b2) -> P
    run_layer(P, W2, b2, maskI, ssrc_ii, ea, off_ii, A, P, n, e, stream);

    // u1 = cgat(x2, uiu, attr_uiu, all, Wu, bu) -> P
    run_layer(P, Wu, bu, nullptr, ssrc_uiu, ea_uiu, off_uiu, A, P, n, e, stream);

    // u2 = cgat(u1, uiu, attr_uiu, all, Wu, bu) -> P
    run_layer(P, Wu, bu, nullptr, ssrc_uiu, ea_uiu, off_uiu, A, P, n, e, stream);

    // out = cos(u2[src_uiu], u2[dst_uiu])  (original edge order)
    norm_kernel<<<((size_t)n * 16 + 255) / 256, 256, 0, stream>>>(P, nrm, n);
    edge_cos_kernel<<<((size_t)e * 16 + 255) / 256, 256, 0, stream>>>(P, src_uiu, dst_uiu, nullptr, nrm, nullptr, out, e);
}

// Round 4
// 848.942 us; speedup vs baseline: 1.5915x; 1.5915x over previous
//
#include <hip/hip_runtime.h>
#include <cstdint>
#include <cmath>

#define D 128
#define SCAN_BS 1024

typedef __attribute__((ext_vector_type(8))) short bf16x8;
typedef __attribute__((ext_vector_type(4))) float f32x4;

// ---------------------------------------------------------------- mask canon
__global__ void mask_canon_kernel(const unsigned char* __restrict__ mraw,
                                  int* __restrict__ mout, int n) {
    int i = blockIdx.x * blockDim.x + threadIdx.x;
    if (i >= n) return;
    bool isbool = (mraw[1] | mraw[2] | mraw[3]) != 0;
    int v;
    if (isbool) v = (mraw[i] != 0);
    else        v = (((const int*)mraw)[i] != 0);
    mout[i] = v;
}

// ---------------------------------------------------------------- node norms
__global__ void norm_kernel(const float* __restrict__ x, float* __restrict__ nrm, int n) {
    int t = blockIdx.x * blockDim.x + threadIdx.x;
    int i = t >> 4, lane = t & 15;
    if (i >= n) return;
    const float4* xr = (const float4*)(x + (size_t)i * D);
    float4 a = xr[lane * 2], b = xr[lane * 2 + 1];
    float acc = a.x*a.x + a.y*a.y + a.z*a.z + a.w*a.w
              + b.x*b.x + b.y*b.y + b.z*b.z + b.w*b.w;
    #pragma unroll
    for (int o = 8; o; o >>= 1) acc += __shfl_xor(acc, o, 16);
    if (lane == 0) nrm[i] = fmaxf(sqrtf(acc), 1e-8f);
}

// ---------------------------------------------------------------- edge cos
__global__ void edge_cos_kernel(const float* __restrict__ x,
                                const int* __restrict__ src,
                                const int* __restrict__ dst,
                                const float* __restrict__ attr,
                                const float* __restrict__ nrm,
                                const int* __restrict__ pos,
                                float* __restrict__ out, int e_total) {
    int t = blockIdx.x * blockDim.x + threadIdx.x;
    int e = t >> 4, lane = t & 15;
    if (e >= e_total) return;
    int s = src[e], d = dst[e];
    const float4* xs = (const float4*)(x + (size_t)s * D);
    const float4* xd = (const float4*)(x + (size_t)d * D);
    float acc = 0.f;
    #pragma unroll
    for (int q = 0; q < 2; q++) {
        float4 a = xs[lane * 2 + q];
        float4 b = xd[lane * 2 + q];
        acc += a.x*b.x + a.y*b.y + a.z*b.z + a.w*b.w;
    }
    #pragma unroll
    for (int o = 8; o; o >>= 1) acc += __shfl_xor(acc, o, 16);
    if (lane == 0) {
        float c = acc / (nrm[s] * nrm[d]);
        out[pos ? pos[e] : e] = attr ? attr[e] * c : c;
    }
}

__global__ void permute_kernel(const float* __restrict__ a, const int* __restrict__ pos,
                               float* __restrict__ out, int e_total) {
    int e = blockIdx.x * blockDim.x + threadIdx.x;
    if (e < e_total) out[pos[e]] = a[e];
}

// ---------------------------------------------------------------- counting sort
__global__ void hist_kernel(const int* __restrict__ dst, int* __restrict__ deg, int e_total) {
    int e = blockIdx.x * blockDim.x + threadIdx.x;
    if (e < e_total) atomicAdd(&deg[dst[e]], 1);
}

__global__ __launch_bounds__(SCAN_BS)
void scan_block_kernel(const int* __restrict__ deg, int* __restrict__ off,
                       int* __restrict__ bsum, int n) {
    __shared__ int s[SCAN_BS];
    int gid = blockIdx.x * SCAN_BS + threadIdx.x;
    int v = (gid < n) ? deg[gid] : 0;
    s[threadIdx.x] = v;
    __syncthreads();
    for (int o = 1; o < SCAN_BS; o <<= 1) {
        int t = (threadIdx.x >= o) ? s[threadIdx.x - o] : 0;
        __syncthreads();
        s[threadIdx.x] += t;
        __syncthreads();
    }
    if (gid < n) off[gid] = s[threadIdx.x] - v;
    if (threadIdx.x == SCAN_BS - 1) bsum[blockIdx.x] = s[SCAN_BS - 1];
}

__global__ void scan_bsum_kernel(int* __restrict__ bsum, int nb) {
    __shared__ int s[256];
    int v = (threadIdx.x < nb) ? bsum[threadIdx.x] : 0;
    s[threadIdx.x] = v;
    __syncthreads();
    for (int o = 1; o < 256; o <<= 1) {
        int t = (threadIdx.x >= o) ? s[threadIdx.x - o] : 0;
        __syncthreads();
        s[threadIdx.x] += t;
        __syncthreads();
    }
    if (threadIdx.x < nb) bsum[threadIdx.x] = s[threadIdx.x] - v;
}

__global__ __launch_bounds__(SCAN_BS)
void add_offsets_kernel(int* __restrict__ off, const int* __restrict__ bsum,
                        int* __restrict__ tmp, int n, int e_total) {
    int gid = blockIdx.x * SCAN_BS + threadIdx.x;
    if (gid < n) {
        off[gid] += bsum[blockIdx.x];
        tmp[gid] = 0;
    }
    if (gid == 0) off[n] = e_total;
}

__global__ void sort_scatter_kernel(const int* __restrict__ src, const int* __restrict__ dst,
                                    const int* __restrict__ off, int* __restrict__ tmp,
                                    int* __restrict__ ssrc, int* __restrict__ pos, int e_total) {
    int e = blockIdx.x * blockDim.x + threadIdx.x;
    if (e >= e_total) return;
    int d = dst[e];
    int p = off[d] + atomicAdd(&tmp[d], 1);
    ssrc[p] = src[e];
    pos[e] = p;
}

// ---------------------------------------------------------------- MFMA GEMM
// h[i][j] = mask[i] ? sum_k x[i][k]*W[j][k] : x[i][j]   (bf16 MFMA, fp32 acc)
// 256 thr = 4 waves x 16 rows = 64 rows/block. x-tile + full W staged as bf16
// in LDS, XOR-swizzled (T2): without it the stride-256B fragment reads are
// 16-way bank conflicts.
__device__ __forceinline__ unsigned short f2b(float f) {
    unsigned u = __float_as_uint(f);
    return (unsigned short)((u + 0x7FFFu + ((u >> 16) & 1u)) >> 16);  // RNE
}
__device__ __forceinline__ int swzbyte(int row, int kb) {
    // row stride 256B; XOR 16B-chunk index with row&7 (keeps 8B alignment)
    return (row << 8) + (kb ^ ((row & 7) << 4));
}

__global__ __launch_bounds__(256)
void gemm_mfma_kernel(const float* __restrict__ x, const float* __restrict__ W,
                      const int* __restrict__ mask, float* __restrict__ h, int n) {
    __shared__ char sXb[64 * 256];    // 64 rows x 128 bf16 (swizzled)
    __shared__ char sWb[128 * 256];   // 128 rows x 128 bf16 (swizzled)
    const int tid = threadIdx.x;
    const int blockRow0 = blockIdx.x * 64;

    // stage x tile (2048 float4) -> bf16
    const float4* xg = (const float4*)x + (size_t)blockRow0 * 32;
    #pragma unroll
    for (int it = 0; it < 8; it++) {
        int f = tid + it * 256;
        int row = f >> 5, kq = f & 31;
        float4 v = (blockRow0 + row < n) ? xg[f] : make_float4(0.f, 0.f, 0.f, 0.f);
        ushort4 b;
        b.x = f2b(v.x); b.y = f2b(v.y); b.z = f2b(v.z); b.w = f2b(v.w);
        *(ushort4*)(sXb + swzbyte(row, kq * 8)) = b;
    }
    // stage W (4096 float4) -> bf16  (sW[j][k] = W[j][k]; B[k][col]=W[col][k])
    const float4* wg = (const float4*)W;
    #pragma unroll
    for (int it = 0; it < 16; it++) {
        int f = tid + it * 256;
        int row = f >> 5, kq = f & 31;
        float4 v = wg[f];
        ushort4 b;
        b.x = f2b(v.x); b.y = f2b(v.y); b.z = f2b(v.z); b.w = f2b(v.w);
        *(ushort4*)(sWb + swzbyte(row, kq * 8)) = b;
    }
    __syncthreads();

    const int wid = tid >> 6, lane = tid & 63;
    const int lrow = lane & 15, kg = lane >> 4;
    f32x4 acc[8];
    #pragma unroll
    for (int j = 0; j < 8; j++) acc[j] = (f32x4)(0.f);

    const int arow = wid * 16 + lrow;
    #pragma unroll
    for (int kk = 0; kk < 4; kk++) {
        int kb = kk * 64 + kg * 16;                   // byte offset of k-slice
        bf16x8 af = *(const bf16x8*)(sXb + swzbyte(arow, kb));
        #pragma unroll
        for (int j = 0; j < 8; j++) {
            bf16x8 bfr = *(const bf16x8*)(sWb + swzbyte(j * 16 + lrow, kb));
            acc[j] = __builtin_amdgcn_mfma_f32_16x16x32_bf16(af, bfr, acc[j], 0, 0, 0);
        }
    }

    // epilogue: C/D layout col=lane&15, row=(lane>>4)*4+reg
    const int growbase = blockRow0 + wid * 16 + kg * 4;
    #pragma unroll
    for (int r = 0; r < 4; r++) {
        int row = growbase + r;
        if (row >= n) continue;
        bool pm = mask ? (mask[row] != 0) : true;
        #pragma unroll
        for (int j = 0; j < 8; j++) {
            int col = j * 16 + lrow;
            float v = acc[j][r];
            if (!pm) v = x[(size_t)row * D + col];   // exact pass-through
            h[(size_t)row * D + col] = v;
        }
    }
}

// ---------------------------------------------------------------- aggregate
__global__ __launch_bounds__(256)
void aggregate_kernel(const float* __restrict__ h,
                      const int* __restrict__ ssrc, const float* __restrict__ ea_s,
                      const int* __restrict__ off,
                      const float* __restrict__ bias, const int* __restrict__ mask,
                      float* __restrict__ out, int n) {
    int t = blockIdx.x * blockDim.x + threadIdx.x;
    int i = t >> 6, lane = t & 63;
    if (i >= n) return;
    float2 hv = ((const float2*)(h + (size_t)i * D))[lane];
    float2* op = (float2*)(out + (size_t)i * D) + lane;
    bool m = mask ? (mask[i] != 0) : true;
    if (!m) { *op = hv; return; }
    int s0 = off[i], s1 = off[i + 1];
    float a0 = 0.f, a1 = 0.f;
    for (int p = s0; p < s1; p++) {
        int s = ssrc[p];
        float a = ea_s[p];
        float2 v = ((const float2*)(h + (size_t)s * D))[lane];
        a0 += a * v.x; a1 += a * v.y;
    }
    float inv = 1.0f / fmaxf((float)(s1 - s0), 1.0f);
    float2 b2 = ((const float2*)bias)[lane];
    float z0 = a0 * inv + hv.x + b2.x;
    float z1 = a1 * inv + hv.y + b2.y;
    float2 o;
    o.x = 1.0f / (1.0f + expf(-z0));
    o.y = 1.0f / (1.0f + expf(-z1));
    *op = o;
}

// ---------------------------------------------------------------- host side
static void build_sorted(const int* src, const int* dst, int* off, int* tmp, int* bsum,
                         int* ssrc, int* pos, int n, int e, hipStream_t stream) {
    int nb = (n + SCAN_BS - 1) / SCAN_BS;
    hipMemsetAsync(tmp, 0, (size_t)n * sizeof(int), stream);
    hist_kernel<<<(e + 255) / 256, 256, 0, stream>>>(dst, tmp, e);
    scan_block_kernel<<<nb, SCAN_BS, 0, stream>>>(tmp, off, bsum, n);
    scan_bsum_kernel<<<1, 256, 0, stream>>>(bsum, nb);
    add_offsets_kernel<<<nb, SCAN_BS, 0, stream>>>(off, bsum, tmp, n, e);
    sort_scatter_kernel<<<(e + 255) / 256, 256, 0, stream>>>(src, dst, off, tmp, ssrc, pos, e);
}

static void run_layer(const float* xin, const float* W, const float* b, const int* mask,
                      const int* ssrc, const float* ea_s, const int* off,
                      float* h, float* outp, int n, int e, hipStream_t stream) {
    gemm_mfma_kernel<<<(n + 63) / 64, 256, 0, stream>>>(xin, W, mask, h, n);
    aggregate_kernel<<<((size_t)n * 64 + 255) / 256, 256, 0, stream>>>(
        h, ssrc, ea_s, off, b, mask, outp, n);
}

extern "C" void kernel_launch(void* const* d_in, const int* in_sizes, int n_in,
                              void* d_out, int out_size, void* d_ws, size_t ws_size,
                              hipStream_t stream) {
    const float* x        = (const float*)d_in[0];
    const float* attr_ii  = (const float*)d_in[1];
    const float* attr_uiu = (const float*)d_in[2];
    const float* W1       = (const float*)d_in[3];
    const float* b1       = (const float*)d_in[4];
    const float* W2       = (const float*)d_in[5];
    const float* b2       = (const float*)d_in[6];
    const float* Wu       = (const float*)d_in[7];
    const float* bu       = (const float*)d_in[8];
    const int*   ei_ii    = (const int*)d_in[9];
    const int*   ei_uiu   = (const int*)d_in[10];
    const unsigned char* mraw = (const unsigned char*)d_in[11];

    const int n = in_sizes[0] / D;      // 100000
    const int e = in_sizes[1];          // 600000
    const size_t ND = (size_t)n * D;

    float* P      = (float*)d_ws;       // node features (updated in place)
    float* A      = P + ND;             // h scratch
    float* ea     = A + ND;             // e (sorted order)
    float* ea_uiu = ea + e;             // e (attr_uiu sorted)
    float* nrm    = ea_uiu + e;         // n
    int* maskI    = (int*)(nrm + n);    // n
    int* tmpA     = maskI + n;          // n
    int* bsum     = tmpA + n;           // 256
    int* off_ii   = bsum + 256;         // n+1
    int* off_uiu  = off_ii + (n + 1);   // n+1
    int* ssrc_ii  = off_uiu + (n + 1);  // e
    int* ssrc_uiu = ssrc_ii + e;        // e
    int* pos_ii   = ssrc_uiu + e;       // e
    int* pos_uiu  = pos_ii + e;         // e

    const int* src_ii  = ei_ii,  * dst_ii  = ei_ii + e;
    const int* src_uiu = ei_uiu, * dst_uiu = ei_uiu + e;
    float* out = (float*)d_out;

    mask_canon_kernel<<<(n + 255) / 256, 256, 0, stream>>>(mraw, maskI, n);

    build_sorted(src_ii,  dst_ii,  off_ii,  tmpA, bsum, ssrc_ii,  pos_ii,  n, e, stream);
    build_sorted(src_uiu, dst_uiu, off_uiu, tmpA, bsum, ssrc_uiu, pos_uiu, n, e, stream);
    permute_kernel<<<(e + 255) / 256, 256, 0, stream>>>(attr_uiu, pos_uiu, ea_uiu, e);

    // ea1 (sorted) = attr_ii * cos(x[src], x[dst])
    norm_kernel<<<((size_t)n * 16 + 255) / 256, 256, 0, stream>>>(x, nrm, n);
    edge_cos_kernel<<<((size_t)e * 16 + 255) / 256, 256, 0, stream>>>(x, src_ii, dst_ii, attr_ii, nrm, pos_ii, ea, e);

    // x1 = cgat(x, ii, ea1, mask, W1, b1) -> P
    run_layer(x, W1, b1, maskI, ssrc_ii, ea, off_ii, A, P, n, e, stream);

    // ea2 (sorted) = attr_ii * cos(x1[src], x1[dst])
    norm_kernel<<<((size_t)n * 16 + 255) / 256, 256, 0, stream>>>(P, nrm, n);
    edge_cos_kernel<<<((size_t)e * 16 + 255) / 256, 256, 0, stream>>>(P, src_ii, dst_ii, attr_ii, nrm, pos_ii, ea, e);

    // x2 = cgat(x1, ii, ea2, mask, W2, b2) -> P
    run_layer(P, W2, b2, maskI, ssrc_ii, ea, off_ii, A, P, n, e, stream);

    // u1 = cgat(x2, uiu, attr_uiu, all, Wu, bu) -> P
    run_layer(P, Wu, bu, nullptr, ssrc_uiu, ea_uiu, off_uiu, A, P, n, e, stream);

    // u2 = cgat(u1, uiu, attr_uiu, all, Wu, bu) -> P
    run_layer(P, Wu, bu, nullptr, ssrc_uiu, ea_uiu, off_uiu, A, P, n, e, stream);

    // out = cos(u2[src_uiu], u2[dst_uiu])  (original edge order)
    norm_kernel<<<((size_t)n * 16 + 255) / 256, 256, 0, stream>>>(P, nrm, n);
    edge_cos_kernel<<<((size_t)e * 16 + 255) / 256, 256, 0, stream>>>(P, src_uiu, dst_uiu, nullptr, nrm, nullptr, out, e);
}

// Round 5
// 672.195 us; speedup vs baseline: 2.0099x; 1.2629x over previous
//
#include <hip/hip_runtime.h>
#include <cstdint>
#include <cmath>

#define D 128
#define SCAN_BS 1024

typedef __attribute__((ext_vector_type(8))) short bf16x8;
typedef __attribute__((ext_vector_type(4))) float f32x4;

__device__ __forceinline__ unsigned short f2b(float f) {
    unsigned u = __float_as_uint(f);
    return (unsigned short)((u + 0x7FFFu + ((u >> 16) & 1u)) >> 16);  // RNE
}
__device__ __forceinline__ float b2f(unsigned short u) {
    return __uint_as_float(((unsigned)u) << 16);
}
__device__ __forceinline__ unsigned pack2(float a, float b) {
    return (unsigned)f2b(a) | ((unsigned)f2b(b) << 16);
}
__device__ __forceinline__ int swzbyte(int row, int b) {
    // row stride 256B; XOR byte-offset bits 4..6 with row&7 (T2 swizzle)
    return (row << 8) + (b ^ ((row & 7) << 4));
}

// ---------------------------------------------------------------- mask canon
__global__ void mask_canon_kernel(const unsigned char* __restrict__ mraw,
                                  int* __restrict__ mout, int n) {
    int i = blockIdx.x * blockDim.x + threadIdx.x;
    if (i >= n) return;
    bool isbool = (mraw[1] | mraw[2] | mraw[3]) != 0;
    int v;
    if (isbool) v = (mraw[i] != 0);
    else        v = (((const int*)mraw)[i] != 0);
    mout[i] = v;
}

// ---------------------------------------------------------------- fp32 -> bf16
__global__ void f32_to_b16_kernel(const float* __restrict__ in,
                                  unsigned short* __restrict__ outb, int n8) {
    int t = blockIdx.x * blockDim.x + threadIdx.x;
    if (t >= n8) return;
    const float4* ip = (const float4*)in + (size_t)t * 2;
    float4 a = ip[0], b = ip[1];
    uint4 o;
    o.x = pack2(a.x, a.y); o.y = pack2(a.z, a.w);
    o.z = pack2(b.x, b.y); o.w = pack2(b.z, b.w);
    ((uint4*)outb)[t] = o;
}

// ---------------------------------------------------------------- bf16 norms
__global__ void norm_b16_kernel(const unsigned short* __restrict__ xb,
                                float* __restrict__ nrm, int n) {
    int t = blockIdx.x * blockDim.x + threadIdx.x;
    int i = t >> 4, lane = t & 15;
    if (i >= n) return;
    uint4 v = ((const uint4*)(xb + (size_t)i * D))[lane];
    float acc = 0.f;
    #pragma unroll
    for (int q = 0; q < 4; q++) {
        unsigned u = (&v.x)[q];
        float f0 = b2f((unsigned short)(u & 0xffff));
        float f1 = b2f((unsigned short)(u >> 16));
        acc += f0 * f0 + f1 * f1;
    }
    #pragma unroll
    for (int o = 8; o; o >>= 1) acc += __shfl_xor(acc, o, 16);
    if (lane == 0) nrm[i] = fmaxf(sqrtf(acc), 1e-8f);
}

// ---------------------------------------------------------------- counting sort
__global__ void hist_kernel(const int* __restrict__ dst, int* __restrict__ deg, int e_total) {
    int e = blockIdx.x * blockDim.x + threadIdx.x;
    if (e < e_total) atomicAdd(&deg[dst[e]], 1);
}

__global__ __launch_bounds__(SCAN_BS)
void scan_block_kernel(const int* __restrict__ deg, int* __restrict__ off,
                       int* __restrict__ bsum, int n) {
    __shared__ int s[SCAN_BS];
    int gid = blockIdx.x * SCAN_BS + threadIdx.x;
    int v = (gid < n) ? deg[gid] : 0;
    s[threadIdx.x] = v;
    __syncthreads();
    for (int o = 1; o < SCAN_BS; o <<= 1) {
        int t = (threadIdx.x >= o) ? s[threadIdx.x - o] : 0;
        __syncthreads();
        s[threadIdx.x] += t;
        __syncthreads();
    }
    if (gid < n) off[gid] = s[threadIdx.x] - v;
    if (threadIdx.x == SCAN_BS - 1) bsum[blockIdx.x] = s[SCAN_BS - 1];
}

__global__ void scan_bsum_kernel(int* __restrict__ bsum, int nb) {
    __shared__ int s[256];
    int v = (threadIdx.x < nb) ? bsum[threadIdx.x] : 0;
    s[threadIdx.x] = v;
    __syncthreads();
    for (int o = 1; o < 256; o <<= 1) {
        int t = (threadIdx.x >= o) ? s[threadIdx.x - o] : 0;
        __syncthreads();
        s[threadIdx.x] += t;
        __syncthreads();
    }
    if (threadIdx.x < nb) bsum[threadIdx.x] = s[threadIdx.x] - v;
}

__global__ __launch_bounds__(SCAN_BS)
void add_offsets_kernel(int* __restrict__ off, const int* __restrict__ bsum,
                        int* __restrict__ tmp, int n, int e_total) {
    int gid = blockIdx.x * SCAN_BS + threadIdx.x;
    if (gid < n) {
        off[gid] += bsum[blockIdx.x];
        tmp[gid] = 0;
    }
    if (gid == 0) off[n] = e_total;
}

__global__ void sort_scatter_kernel(const int* __restrict__ src, const int* __restrict__ dst,
                                    const int* __restrict__ off, int* __restrict__ tmp,
                                    int* __restrict__ ssrc, int* __restrict__ pos, int e_total) {
    int e = blockIdx.x * blockDim.x + threadIdx.x;
    if (e >= e_total) return;
    int d = dst[e];
    int p = off[d] + atomicAdd(&tmp[d], 1);
    ssrc[p] = src[e];
    pos[e] = p;
}

__global__ void permute_kernel(const float* __restrict__ a, const int* __restrict__ pos,
                               float* __restrict__ out, int e_total) {
    int e = blockIdx.x * blockDim.x + threadIdx.x;
    if (e < e_total) out[pos[e]] = a[e];
}

// ---------------------------------------------------------------- MFMA GEMM
// hb[i][j] = mask[i] ? bf16(sum_k xb[i][k]*Wb[j][k]) : xb[i][j]
// bf16 in / bf16 out, fp32 MFMA accumulation. 4 waves x 16 rows = 64 rows/blk.
__global__ __launch_bounds__(256)
void gemm_mfma_kernel(const unsigned short* __restrict__ xb,
                      const unsigned short* __restrict__ Wb,
                      const int* __restrict__ mask,
                      unsigned short* __restrict__ hb, int n) {
    __shared__ char sXb[64 * 256];    // 64 rows x 128 bf16 (swizzled)
    __shared__ char sWb[128 * 256];   // 128 rows x 128 bf16 (swizzled)
    const int tid = threadIdx.x;
    const int blockRow0 = blockIdx.x * 64;

    const uint4* xg = (const uint4*)xb + (size_t)blockRow0 * 16;
    #pragma unroll
    for (int it = 0; it < 4; it++) {
        int f = tid + it * 256;
        int row = f >> 4, kc = f & 15;
        uint4 v = make_uint4(0, 0, 0, 0);
        if (blockRow0 + row < n) v = xg[f];
        *(uint4*)(sXb + swzbyte(row, kc * 16)) = v;
    }
    const uint4* wg = (const uint4*)Wb;
    #pragma unroll
    for (int it = 0; it < 8; it++) {
        int f = tid + it * 256;
        int row = f >> 4, kc = f & 15;
        *(uint4*)(sWb + swzbyte(row, kc * 16)) = wg[f];
    }
    __syncthreads();

    const int wid = tid >> 6, lane = tid & 63;
    const int lrow = lane & 15, kg = lane >> 4;
    f32x4 acc[8];
    #pragma unroll
    for (int j = 0; j < 8; j++) acc[j] = (f32x4)(0.f);

    const int arow = wid * 16 + lrow;
    #pragma unroll
    for (int kk = 0; kk < 4; kk++) {
        int kb = kk * 64 + kg * 16;
        bf16x8 af = *(const bf16x8*)(sXb + swzbyte(arow, kb));
        #pragma unroll
        for (int j = 0; j < 8; j++) {
            bf16x8 bfr = *(const bf16x8*)(sWb + swzbyte(j * 16 + lrow, kb));
            acc[j] = __builtin_amdgcn_mfma_f32_16x16x32_bf16(af, bfr, acc[j], 0, 0, 0);
        }
    }

    // C/D layout: col=lane&15, row=(lane>>4)*4+reg
    const int growbase = blockRow0 + wid * 16 + kg * 4;
    const int lrbase = wid * 16 + kg * 4;
    #pragma unroll
    for (int r = 0; r < 4; r++) {
        int row = growbase + r;
        if (row >= n) continue;
        bool pm = mask ? (mask[row] != 0) : true;
        int lr = lrbase + r;
        #pragma unroll
        for (int j = 0; j < 8; j++) {
            int col = j * 16 + lrow;
            unsigned short o;
            if (pm) o = f2b(acc[j][r]);
            else    o = *(const unsigned short*)(sXb + (lr << 8) + ((2 * col) ^ ((lr & 7) << 4)));
            hb[(size_t)row * D + col] = o;
        }
    }
}

// ---------------------------------------------------------------- fused agg
// One 64-lane wave per dst node i; lane owns elems {2lane, 2lane+1}.
// If xb != null: c = attr_s[p] * dot(xb[s],xb[i]) / (nrm[s]*nrm[i])  (cos fused)
// else:          c = attr_s[p]
// out[i] = mask[i] ? sigmoid(mean_p(c*h[s]) + h[i] + b) : h[i]   (bf16 out)
__global__ __launch_bounds__(256)
void fused_agg_kernel(const unsigned short* __restrict__ hb,
                      const unsigned short* __restrict__ xb,
                      const float* __restrict__ nrm,
                      const int* __restrict__ ssrc, const float* __restrict__ attr_s,
                      const int* __restrict__ off,
                      const float* __restrict__ bias, const int* __restrict__ mask,
                      unsigned short* __restrict__ outb, int n) {
    int t = blockIdx.x * blockDim.x + threadIdx.x;
    int i = t >> 6, lane = t & 63;
    if (i >= n) return;
    unsigned hvu = ((const unsigned*)(hb + (size_t)i * D))[lane];
    unsigned* op = (unsigned*)(outb + (size_t)i * D) + lane;
    bool m = mask ? (mask[i] != 0) : true;
    if (!m) { *op = hvu; return; }
    float h0 = b2f((unsigned short)(hvu & 0xffff));
    float h1 = b2f((unsigned short)(hvu >> 16));

    float xd0 = 0.f, xd1 = 0.f, inv_ni = 0.f;
    if (xb) {
        unsigned xdu = ((const unsigned*)(xb + (size_t)i * D))[lane];
        xd0 = b2f((unsigned short)(xdu & 0xffff));
        xd1 = b2f((unsigned short)(xdu >> 16));
        inv_ni = 1.0f / nrm[i];
    }

    int s0 = off[i], s1 = off[i + 1];
    float a0 = 0.f, a1 = 0.f;
    for (int p = s0; p < s1; p++) {
        int s = ssrc[p];
        float a = attr_s[p];
        float c;
        if (xb) {
            unsigned xsu = ((const unsigned*)(xb + (size_t)s * D))[lane];
            float v0 = b2f((unsigned short)(xsu & 0xffff));
            float v1 = b2f((unsigned short)(xsu >> 16));
            float pr = v0 * xd0 + v1 * xd1;
            #pragma unroll
            for (int o = 32; o; o >>= 1) pr += __shfl_xor(pr, o, 64);
            c = a * pr * inv_ni / nrm[s];
        } else {
            c = a;
        }
        unsigned hsu = ((const unsigned*)(hb + (size_t)s * D))[lane];
        a0 += c * b2f((unsigned short)(hsu & 0xffff));
        a1 += c * b2f((unsigned short)(hsu >> 16));
    }
    float inv = 1.0f / fmaxf((float)(s1 - s0), 1.0f);
    float2 bv = ((const float2*)bias)[lane];
    float z0 = a0 * inv + h0 + bv.x;
    float z1 = a1 * inv + h1 + bv.y;
    float o0 = 1.0f / (1.0f + expf(-z0));
    float o1 = 1.0f / (1.0f + expf(-z1));
    *op = pack2(o0, o1);
}

// ---------------------------------------------------------------- final cos
__global__ void edge_cos_b16_kernel(const unsigned short* __restrict__ xb,
                                    const int* __restrict__ src,
                                    const int* __restrict__ dst,
                                    const float* __restrict__ nrm,
                                    float* __restrict__ out, int e_total) {
    int t = blockIdx.x * blockDim.x + threadIdx.x;
    int e = t >> 4, lane = t & 15;
    if (e >= e_total) return;
    int s = src[e], d = dst[e];
    uint4 a = ((const uint4*)(xb + (size_t)s * D))[lane];
    uint4 b = ((const uint4*)(xb + (size_t)d * D))[lane];
    float acc = 0.f;
    #pragma unroll
    for (int q = 0; q < 4; q++) {
        unsigned ua = (&a.x)[q], ub = (&b.x)[q];
        acc += b2f((unsigned short)(ua & 0xffff)) * b2f((unsigned short)(ub & 0xffff));
        acc += b2f((unsigned short)(ua >> 16))    * b2f((unsigned short)(ub >> 16));
    }
    #pragma unroll
    for (int o = 8; o; o >>= 1) acc += __shfl_xor(acc, o, 16);
    if (lane == 0) out[e] = acc / (nrm[s] * nrm[d]);
}

// ---------------------------------------------------------------- host side
static void build_sorted(const int* src, const int* dst, int* off, int* tmp, int* bsum,
                         int* ssrc, int* pos, int n, int e, hipStream_t stream) {
    int nb = (n + SCAN_BS - 1) / SCAN_BS;
    hipMemsetAsync(tmp, 0, (size_t)n * sizeof(int), stream);
    hist_kernel<<<(e + 255) / 256, 256, 0, stream>>>(dst, tmp, e);
    scan_block_kernel<<<nb, SCAN_BS, 0, stream>>>(tmp, off, bsum, n);
    scan_bsum_kernel<<<1, 256, 0, stream>>>(bsum, nb);
    add_offsets_kernel<<<nb, SCAN_BS, 0, stream>>>(off, bsum, tmp, n, e);
    sort_scatter_kernel<<<(e + 255) / 256, 256, 0, stream>>>(src, dst, off, tmp, ssrc, pos, e);
}

extern "C" void kernel_launch(void* const* d_in, const int* in_sizes, int n_in,
                              void* d_out, int out_size, void* d_ws, size_t ws_size,
                              hipStream_t stream) {
    const float* x        = (const float*)d_in[0];
    const float* attr_ii  = (const float*)d_in[1];
    const float* attr_uiu = (const float*)d_in[2];
    const float* W1       = (const float*)d_in[3];
    const float* b1       = (const float*)d_in[4];
    const float* W2       = (const float*)d_in[5];
    const float* b2       = (const float*)d_in[6];
    const float* Wu       = (const float*)d_in[7];
    const float* bu       = (const float*)d_in[8];
    const int*   ei_ii    = (const int*)d_in[9];
    const int*   ei_uiu   = (const int*)d_in[10];
    const unsigned char* mraw = (const unsigned char*)d_in[11];

    const int n = in_sizes[0] / D;      // 100000
    const int e = in_sizes[1];          // 600000
    const size_t ND = (size_t)n * D;

    unsigned short* Ab  = (unsigned short*)d_ws;   // h bf16 (per layer)
    unsigned short* Bb0 = Ab + ND;                 // node features ping
    unsigned short* Bb1 = Bb0 + ND;                // node features pong
    unsigned short* Wb1 = Bb1 + ND;                // 16384 each
    unsigned short* Wb2 = Wb1 + 16384;
    unsigned short* Wbu = Wb2 + 16384;
    float* attr_ii_s  = (float*)(Wbu + 16384);     // e
    float* attr_uiu_s = attr_ii_s + e;             // e
    float* nrm  = attr_uiu_s + e;                  // n
    int* maskI  = (int*)(nrm + n);                 // n
    int* tmpA   = maskI + n;                       // n
    int* bsum   = tmpA + n;                        // 256
    int* off_ii = bsum + 256;                      // n+1
    int* off_uiu = off_ii + (n + 1);               // n+1
    int* ssrc_ii = off_uiu + (n + 1);              // e
    int* ssrc_uiu = ssrc_ii + e;                   // e
    // transient (preprocessing only): alias into Ab region
    int* pos_ii  = (int*)Ab;                       // e
    int* pos_uiu = pos_ii + e;                     // e

    const int* src_ii  = ei_ii,  * dst_ii  = ei_ii + e;
    const int* src_uiu = ei_uiu, * dst_uiu = ei_uiu + e;
    float* out = (float*)d_out;

    const int gN16 = ((size_t)n * 16 + 255) / 256;
    const int gE16 = ((size_t)e * 16 + 255) / 256;
    const int gN64 = ((size_t)n * 64 + 255) / 256;
    const int gGemm = (n + 63) / 64;

    mask_canon_kernel<<<(n + 255) / 256, 256, 0, stream>>>(mraw, maskI, n);

    // sort both graphs by dst; permute attrs into sorted order
    build_sorted(src_ii,  dst_ii,  off_ii,  tmpA, bsum, ssrc_ii,  pos_ii,  n, e, stream);
    build_sorted(src_uiu, dst_uiu, off_uiu, tmpA, bsum, ssrc_uiu, pos_uiu, n, e, stream);
    permute_kernel<<<(e + 255) / 256, 256, 0, stream>>>(attr_ii,  pos_ii,  attr_ii_s,  e);
    permute_kernel<<<(e + 255) / 256, 256, 0, stream>>>(attr_uiu, pos_uiu, attr_uiu_s, e);

    // convert x and weights to bf16
    f32_to_b16_kernel<<<((int)(ND / 8) + 255) / 256, 256, 0, stream>>>(x, Bb0, (int)(ND / 8));
    f32_to_b16_kernel<<<8, 256, 0, stream>>>(W1, Wb1, 2048);
    f32_to_b16_kernel<<<8, 256, 0, stream>>>(W2, Wb2, 2048);
    f32_to_b16_kernel<<<8, 256, 0, stream>>>(Wu, Wbu, 2048);

    // L1: x1 = cgat(x, ii, cos-fused, mask, W1, b1)   Bb0 -> Bb1
    norm_b16_kernel<<<gN16, 256, 0, stream>>>(Bb0, nrm, n);
    gemm_mfma_kernel<<<gGemm, 256, 0, stream>>>(Bb0, Wb1, maskI, Ab, n);
    fused_agg_kernel<<<gN64, 256, 0, stream>>>(Ab, Bb0, nrm, ssrc_ii, attr_ii_s, off_ii,
                                               b1, maskI, Bb1, n);

    // L2: x2 = cgat(x1, ii, cos-fused, mask, W2, b2)  Bb1 -> Bb0
    norm_b16_kernel<<<gN16, 256, 0, stream>>>(Bb1, nrm, n);
    gemm_mfma_kernel<<<gGemm, 256, 0, stream>>>(Bb1, Wb2, maskI, Ab, n);
    fused_agg_kernel<<<gN64, 256, 0, stream>>>(Ab, Bb1, nrm, ssrc_ii, attr_ii_s, off_ii,
                                               b2, maskI, Bb0, n);

    // L3: u1 = cgat(x2, uiu, attr, all, Wu, bu)       Bb0 -> Bb1
    gemm_mfma_kernel<<<gGemm, 256, 0, stream>>>(Bb0, Wbu, nullptr, Ab, n);
    fused_agg_kernel<<<gN64, 256, 0, stream>>>(Ab, nullptr, nullptr, ssrc_uiu, attr_uiu_s,
                                               off_uiu, bu, nullptr, Bb1, n);

    // L4: u2 = cgat(u1, uiu, attr, all, Wu, bu)       Bb1 -> Bb0
    gemm_mfma_kernel<<<gGemm, 256, 0, stream>>>(Bb1, Wbu, nullptr, Ab, n);
    fused_agg_kernel<<<gN64, 256, 0, stream>>>(Ab, nullptr, nullptr, ssrc_uiu, attr_uiu_s,
                                               off_uiu, bu, nullptr, Bb0, n);

    // out = cos(u2[src_uiu], u2[dst_uiu])  (original edge order)
    norm_b16_kernel<<<gN16, 256, 0, stream>>>(Bb0, nrm, n);
    edge_cos_b16_kernel<<<gE16, 256, 0, stream>>>(Bb0, src_uiu, dst_uiu, nrm, out, e);
}

// Round 6
// 560.982 us; speedup vs baseline: 2.4084x; 1.1982x over previous
//
#include <hip/hip_runtime.h>
#include <cstdint>
#include <cmath>

#define D 128
#define SCAN_BS 1024

typedef __attribute__((ext_vector_type(8))) short bf16x8;
typedef __attribute__((ext_vector_type(4))) float f32x4;

__device__ __forceinline__ unsigned short f2b(float f) {
    unsigned u = __float_as_uint(f);
    return (unsigned short)((u + 0x7FFFu + ((u >> 16) & 1u)) >> 16);  // RNE
}
__device__ __forceinline__ float b2f(unsigned short u) {
    return __uint_as_float(((unsigned)u) << 16);
}
__device__ __forceinline__ unsigned pack2(float a, float b) {
    return (unsigned)f2b(a) | ((unsigned)f2b(b) << 16);
}
__device__ __forceinline__ int swzbyte(int row, int b) {
    return (row << 8) + (b ^ ((row & 7) << 4));   // T2 swizzle, 256B row stride
}

// ---------------------------------------------------------------- mask canon
__global__ void mask_canon_kernel(const unsigned char* __restrict__ mraw,
                                  int* __restrict__ mout, int n) {
    int i = blockIdx.x * blockDim.x + threadIdx.x;
    if (i >= n) return;
    bool isbool = (mraw[1] | mraw[2] | mraw[3]) != 0;
    int v;
    if (isbool) v = (mraw[i] != 0);
    else        v = (((const int*)mraw)[i] != 0);
    mout[i] = v;
}

// ---------------------------------------------------------------- fp32 -> bf16
__global__ void f32_to_b16_kernel(const float* __restrict__ in,
                                  unsigned short* __restrict__ outb, int n8) {
    int t = blockIdx.x * blockDim.x + threadIdx.x;
    if (t >= n8) return;
    const float4* ip = (const float4*)in + (size_t)t * 2;
    float4 a = ip[0], b = ip[1];
    uint4 o;
    o.x = pack2(a.x, a.y); o.y = pack2(a.z, a.w);
    o.z = pack2(b.x, b.y); o.w = pack2(b.z, b.w);
    ((uint4*)outb)[t] = o;
}

// ---------------------------------------------------------------- bf16 rnorm
// writes 1/max(||row||,eps) so consumers multiply instead of divide
__global__ void rnorm_b16_kernel(const unsigned short* __restrict__ xb,
                                 float* __restrict__ rnrm, int n) {
    int t = blockIdx.x * blockDim.x + threadIdx.x;
    int i = t >> 4, lane = t & 15;
    if (i >= n) return;
    uint4 v = ((const uint4*)(xb + (size_t)i * D))[lane];
    float acc = 0.f;
    #pragma unroll
    for (int q = 0; q < 4; q++) {
        unsigned u = (&v.x)[q];
        float f0 = b2f((unsigned short)(u & 0xffff));
        float f1 = b2f((unsigned short)(u >> 16));
        acc += f0 * f0 + f1 * f1;
    }
    #pragma unroll
    for (int o = 8; o; o >>= 1) acc += __shfl_xor(acc, o, 16);
    if (lane == 0) rnrm[i] = 1.0f / fmaxf(sqrtf(acc), 1e-8f);
}

// ---------------------------------------------------------------- counting sort
__global__ void hist_kernel(const int* __restrict__ dst, int* __restrict__ deg, int e_total) {
    int e = blockIdx.x * blockDim.x + threadIdx.x;
    if (e < e_total) atomicAdd(&deg[dst[e]], 1);
}

__global__ __launch_bounds__(SCAN_BS)
void scan_block_kernel(const int* __restrict__ deg, int* __restrict__ off,
                       int* __restrict__ bsum, int n) {
    __shared__ int s[SCAN_BS];
    int gid = blockIdx.x * SCAN_BS + threadIdx.x;
    int v = (gid < n) ? deg[gid] : 0;
    s[threadIdx.x] = v;
    __syncthreads();
    for (int o = 1; o < SCAN_BS; o <<= 1) {
        int t = (threadIdx.x >= o) ? s[threadIdx.x - o] : 0;
        __syncthreads();
        s[threadIdx.x] += t;
        __syncthreads();
    }
    if (gid < n) off[gid] = s[threadIdx.x] - v;
    if (threadIdx.x == SCAN_BS - 1) bsum[blockIdx.x] = s[SCAN_BS - 1];
}

__global__ void scan_bsum_kernel(int* __restrict__ bsum, int nb) {
    __shared__ int s[256];
    int v = (threadIdx.x < nb) ? bsum[threadIdx.x] : 0;
    s[threadIdx.x] = v;
    __syncthreads();
    for (int o = 1; o < 256; o <<= 1) {
        int t = (threadIdx.x >= o) ? s[threadIdx.x - o] : 0;
        __syncthreads();
        s[threadIdx.x] += t;
        __syncthreads();
    }
    if (threadIdx.x < nb) bsum[threadIdx.x] = s[threadIdx.x] - v;
}

__global__ __launch_bounds__(SCAN_BS)
void add_offsets_kernel(int* __restrict__ off, const int* __restrict__ bsum,
                        int* __restrict__ tmp, int n, int e_total) {
    int gid = blockIdx.x * SCAN_BS + threadIdx.x;
    if (gid < n) {
        off[gid] += bsum[blockIdx.x];
        tmp[gid] = 0;
    }
    if (gid == 0) off[n] = e_total;
}

__global__ void sort_scatter_kernel(const int* __restrict__ src, const int* __restrict__ dst,
                                    const int* __restrict__ off, int* __restrict__ tmp,
                                    int* __restrict__ ssrc, int* __restrict__ pos, int e_total) {
    int e = blockIdx.x * blockDim.x + threadIdx.x;
    if (e >= e_total) return;
    int d = dst[e];
    int p = off[d] + atomicAdd(&tmp[d], 1);
    ssrc[p] = src[e];
    pos[e] = p;
}

__global__ void permute_kernel(const float* __restrict__ a, const int* __restrict__ pos,
                               float* __restrict__ out, int e_total) {
    int e = blockIdx.x * blockDim.x + threadIdx.x;
    if (e < e_total) out[pos[e]] = a[e];
}

// ---------------------------------------------------------------- MFMA GEMM
__global__ __launch_bounds__(256)
void gemm_mfma_kernel(const unsigned short* __restrict__ xb,
                      const unsigned short* __restrict__ Wb,
                      const int* __restrict__ mask,
                      unsigned short* __restrict__ hb, int n) {
    __shared__ char sXb[64 * 256];
    __shared__ char sWb[128 * 256];
    const int tid = threadIdx.x;
    const int blockRow0 = blockIdx.x * 64;

    const uint4* xg = (const uint4*)xb + (size_t)blockRow0 * 16;
    #pragma unroll
    for (int it = 0; it < 4; it++) {
        int f = tid + it * 256;
        int row = f >> 4, kc = f & 15;
        uint4 v = make_uint4(0, 0, 0, 0);
        if (blockRow0 + row < n) v = xg[f];
        *(uint4*)(sXb + swzbyte(row, kc * 16)) = v;
    }
    const uint4* wg = (const uint4*)Wb;
    #pragma unroll
    for (int it = 0; it < 8; it++) {
        int f = tid + it * 256;
        int row = f >> 4, kc = f & 15;
        *(uint4*)(sWb + swzbyte(row, kc * 16)) = wg[f];
    }
    __syncthreads();

    const int wid = tid >> 6, lane = tid & 63;
    const int lrow = lane & 15, kg = lane >> 4;
    f32x4 acc[8];
    #pragma unroll
    for (int j = 0; j < 8; j++) acc[j] = (f32x4)(0.f);

    const int arow = wid * 16 + lrow;
    #pragma unroll
    for (int kk = 0; kk < 4; kk++) {
        int kb = kk * 64 + kg * 16;
        bf16x8 af = *(const bf16x8*)(sXb + swzbyte(arow, kb));
        #pragma unroll
        for (int j = 0; j < 8; j++) {
            bf16x8 bfr = *(const bf16x8*)(sWb + swzbyte(j * 16 + lrow, kb));
            acc[j] = __builtin_amdgcn_mfma_f32_16x16x32_bf16(af, bfr, acc[j], 0, 0, 0);
        }
    }

    const int growbase = blockRow0 + wid * 16 + kg * 4;
    const int lrbase = wid * 16 + kg * 4;
    #pragma unroll
    for (int r = 0; r < 4; r++) {
        int row = growbase + r;
        if (row >= n) continue;
        bool pm = mask ? (mask[row] != 0) : true;
        int lr = lrbase + r;
        #pragma unroll
        for (int j = 0; j < 8; j++) {
            int col = j * 16 + lrow;
            unsigned short o;
            if (pm) o = f2b(acc[j][r]);
            else    o = *(const unsigned short*)(sXb + (lr << 8) + ((2 * col) ^ ((lr & 7) << 4)));
            hb[(size_t)row * D + col] = o;
        }
    }
}

// ---------------------------------------------------------------- fused agg
// One wave per dst node, split into 4 edge-groups x 16 lanes. Lane owns 8
// elements (uint4 = 16B): a 16-lane group reads one 256B row coalesced.
// Group g walks edges p = s0+g, s0+g+4, ... -> 4 independent gather chains.
__global__ __launch_bounds__(256)
void fused_agg_kernel(const unsigned short* __restrict__ hb,
                      const unsigned short* __restrict__ xb,   // null: c = attr only
                      const float* __restrict__ rnrm,
                      const int* __restrict__ ssrc, const float* __restrict__ attr_s,
                      const int* __restrict__ off,
                      const float* __restrict__ bias, const int* __restrict__ mask,
                      unsigned short* __restrict__ outb, int n) {
    int t = blockIdx.x * blockDim.x + threadIdx.x;
    int i = t >> 6, lane = t & 63;
    if (i >= n) return;
    int g = lane >> 4, sl = lane & 15;
    uint4 hv = ((const uint4*)(hb + (size_t)i * D))[sl];
    uint4* op = (uint4*)(outb + (size_t)i * D) + sl;
    bool m = mask ? (mask[i] != 0) : true;
    if (!m) { if (g == 0) *op = hv; return; }

    float xd[8];
    float ri = 0.f;
    if (xb) {
        uint4 xv = ((const uint4*)(xb + (size_t)i * D))[sl];
        #pragma unroll
        for (int q = 0; q < 4; q++) {
            unsigned u = (&xv.x)[q];
            xd[2*q]   = b2f((unsigned short)(u & 0xffff));
            xd[2*q+1] = b2f((unsigned short)(u >> 16));
        }
        ri = rnrm[i];
    }

    int s0 = off[i], s1 = off[i + 1];
    float acc[8];
    #pragma unroll
    for (int k = 0; k < 8; k++) acc[k] = 0.f;

    for (int p = s0 + g; p < s1; p += 4) {
        int s = ssrc[p];
        float a = attr_s[p];
        uint4 hs = ((const uint4*)(hb + (size_t)s * D))[sl];   // in flight early
        float c;
        if (xb) {
            uint4 xs = ((const uint4*)(xb + (size_t)s * D))[sl];
            float pr = 0.f;
            #pragma unroll
            for (int q = 0; q < 4; q++) {
                unsigned u = (&xs.x)[q];
                pr += b2f((unsigned short)(u & 0xffff)) * xd[2*q];
                pr += b2f((unsigned short)(u >> 16))    * xd[2*q+1];
            }
            #pragma unroll
            for (int o = 8; o; o >>= 1) pr += __shfl_xor(pr, o, 64);  // within 16-lane group
            c = a * pr * ri * rnrm[s];
        } else {
            c = a;
        }
        #pragma unroll
        for (int q = 0; q < 4; q++) {
            unsigned u = (&hs.x)[q];
            acc[2*q]   += c * b2f((unsigned short)(u & 0xffff));
            acc[2*q+1] += c * b2f((unsigned short)(u >> 16));
        }
    }

    // combine the 4 groups (lanes sl, sl+16, sl+32, sl+48)
    #pragma unroll
    for (int k = 0; k < 8; k++) {
        acc[k] += __shfl_xor(acc[k], 16, 64);
        acc[k] += __shfl_xor(acc[k], 32, 64);
    }
    if (g != 0) return;

    float inv = 1.0f / fmaxf((float)(s1 - s0), 1.0f);
    const float4* bp = (const float4*)(bias + 8 * sl);
    float4 bv0 = bp[0], bv1 = bp[1];
    float bb[8] = {bv0.x, bv0.y, bv0.z, bv0.w, bv1.x, bv1.y, bv1.z, bv1.w};
    uint4 o;
    #pragma unroll
    for (int q = 0; q < 4; q++) {
        unsigned u = (&hv.x)[q];
        float h0 = b2f((unsigned short)(u & 0xffff));
        float h1 = b2f((unsigned short)(u >> 16));
        float z0 = acc[2*q] * inv + h0 + bb[2*q];
        float z1 = acc[2*q+1] * inv + h1 + bb[2*q+1];
        float o0 = 1.0f / (1.0f + expf(-z0));
        float o1 = 1.0f / (1.0f + expf(-z1));
        (&o.x)[q] = pack2(o0, o1);
    }
    *op = o;
}

// ---------------------------------------------------------------- final cos
__global__ void edge_cos_b16_kernel(const unsigned short* __restrict__ xb,
                                    const int* __restrict__ src,
                                    const int* __restrict__ dst,
                                    const float* __restrict__ rnrm,
                                    float* __restrict__ out, int e_total) {
    int t = blockIdx.x * blockDim.x + threadIdx.x;
    int e = t >> 4, lane = t & 15;
    if (e >= e_total) return;
    int s = src[e], d = dst[e];
    uint4 a = ((const uint4*)(xb + (size_t)s * D))[lane];
    uint4 b = ((const uint4*)(xb + (size_t)d * D))[lane];
    float acc = 0.f;
    #pragma unroll
    for (int q = 0; q < 4; q++) {
        unsigned ua = (&a.x)[q], ub = (&b.x)[q];
        acc += b2f((unsigned short)(ua & 0xffff)) * b2f((unsigned short)(ub & 0xffff));
        acc += b2f((unsigned short)(ua >> 16))    * b2f((unsigned short)(ub >> 16));
    }
    #pragma unroll
    for (int o = 8; o; o >>= 1) acc += __shfl_xor(acc, o, 16);
    if (lane == 0) out[e] = acc * rnrm[s] * rnrm[d];
}

// ---------------------------------------------------------------- host side
static void build_sorted(const int* src, const int* dst, int* off, int* tmp, int* bsum,
                         int* ssrc, int* pos, int n, int e, hipStream_t stream) {
    int nb = (n + SCAN_BS - 1) / SCAN_BS;
    hipMemsetAsync(tmp, 0, (size_t)n * sizeof(int), stream);
    hist_kernel<<<(e + 255) / 256, 256, 0, stream>>>(dst, tmp, e);
    scan_block_kernel<<<nb, SCAN_BS, 0, stream>>>(tmp, off, bsum, n);
    scan_bsum_kernel<<<1, 256, 0, stream>>>(bsum, nb);
    add_offsets_kernel<<<nb, SCAN_BS, 0, stream>>>(off, bsum, tmp, n, e);
    sort_scatter_kernel<<<(e + 255) / 256, 256, 0, stream>>>(src, dst, off, tmp, ssrc, pos, e);
}

extern "C" void kernel_launch(void* const* d_in, const int* in_sizes, int n_in,
                              void* d_out, int out_size, void* d_ws, size_t ws_size,
                              hipStream_t stream) {
    const float* x        = (const float*)d_in[0];
    const float* attr_ii  = (const float*)d_in[1];
    const float* attr_uiu = (const float*)d_in[2];
    const float* W1       = (const float*)d_in[3];
    const float* b1       = (const float*)d_in[4];
    const float* W2       = (const float*)d_in[5];
    const float* b2       = (const float*)d_in[6];
    const float* Wu       = (const float*)d_in[7];
    const float* bu       = (const float*)d_in[8];
    const int*   ei_ii    = (const int*)d_in[9];
    const int*   ei_uiu   = (const int*)d_in[10];
    const unsigned char* mraw = (const unsigned char*)d_in[11];

    const int n = in_sizes[0] / D;      // 100000
    const int e = in_sizes[1];          // 600000
    const size_t ND = (size_t)n * D;

    unsigned short* Ab  = (unsigned short*)d_ws;   // h bf16 (per layer)
    unsigned short* Bb0 = Ab + ND;                 // node features ping
    unsigned short* Bb1 = Bb0 + ND;                // node features pong
    unsigned short* Wb1 = Bb1 + ND;
    unsigned short* Wb2 = Wb1 + 16384;
    unsigned short* Wbu = Wb2 + 16384;
    float* attr_ii_s  = (float*)(Wbu + 16384);     // e
    float* attr_uiu_s = attr_ii_s + e;             // e
    float* rnrm = attr_uiu_s + e;                  // n
    int* maskI  = (int*)(rnrm + n);                // n
    int* tmpA   = maskI + n;                       // n
    int* bsum   = tmpA + n;                        // 256
    int* off_ii = bsum + 256;                      // n+1
    int* off_uiu = off_ii + (n + 1);               // n+1
    int* ssrc_ii = off_uiu + (n + 1);              // e
    int* ssrc_uiu = ssrc_ii + e;                   // e
    // transient (preprocessing only): alias into Ab region
    int* pos_ii  = (int*)Ab;                       // e
    int* pos_uiu = pos_ii + e;                     // e

    const int* src_ii  = ei_ii,  * dst_ii  = ei_ii + e;
    const int* src_uiu = ei_uiu, * dst_uiu = ei_uiu + e;
    float* out = (float*)d_out;

    const int gN16 = ((size_t)n * 16 + 255) / 256;
    const int gE16 = ((size_t)e * 16 + 255) / 256;
    const int gN64 = ((size_t)n * 64 + 255) / 256;
    const int gGemm = (n + 63) / 64;

    mask_canon_kernel<<<(n + 255) / 256, 256, 0, stream>>>(mraw, maskI, n);

    build_sorted(src_ii,  dst_ii,  off_ii,  tmpA, bsum, ssrc_ii,  pos_ii,  n, e, stream);
    build_sorted(src_uiu, dst_uiu, off_uiu, tmpA, bsum, ssrc_uiu, pos_uiu, n, e, stream);
    permute_kernel<<<(e + 255) / 256, 256, 0, stream>>>(attr_ii,  pos_ii,  attr_ii_s,  e);
    permute_kernel<<<(e + 255) / 256, 256, 0, stream>>>(attr_uiu, pos_uiu, attr_uiu_s, e);

    f32_to_b16_kernel<<<((int)(ND / 8) + 255) / 256, 256, 0, stream>>>(x, Bb0, (int)(ND / 8));
    f32_to_b16_kernel<<<8, 256, 0, stream>>>(W1, Wb1, 2048);
    f32_to_b16_kernel<<<8, 256, 0, stream>>>(W2, Wb2, 2048);
    f32_to_b16_kernel<<<8, 256, 0, stream>>>(Wu, Wbu, 2048);

    // L1: x1 = cgat(x, ii, cos-fused, mask, W1, b1)   Bb0 -> Bb1
    rnorm_b16_kernel<<<gN16, 256, 0, stream>>>(Bb0, rnrm, n);
    gemm_mfma_kernel<<<gGemm, 256, 0, stream>>>(Bb0, Wb1, maskI, Ab, n);
    fused_agg_kernel<<<gN64, 256, 0, stream>>>(Ab, Bb0, rnrm, ssrc_ii, attr_ii_s, off_ii,
                                               b1, maskI, Bb1, n);

    // L2: x2 = cgat(x1, ii, cos-fused, mask, W2, b2)  Bb1 -> Bb0
    rnorm_b16_kernel<<<gN16, 256, 0, stream>>>(Bb1, rnrm, n);
    gemm_mfma_kernel<<<gGemm, 256, 0, stream>>>(Bb1, Wb2, maskI, Ab, n);
    fused_agg_kernel<<<gN64, 256, 0, stream>>>(Ab, Bb1, rnrm, ssrc_ii, attr_ii_s, off_ii,
                                               b2, maskI, Bb0, n);

    // L3: u1 = cgat(x2, uiu, attr, all, Wu, bu)       Bb0 -> Bb1
    gemm_mfma_kernel<<<gGemm, 256, 0, stream>>>(Bb0, Wbu, nullptr, Ab, n);
    fused_agg_kernel<<<gN64, 256, 0, stream>>>(Ab, nullptr, nullptr, ssrc_uiu, attr_uiu_s,
                                               off_uiu, bu, nullptr, Bb1, n);

    // L4: u2 = cgat(u1, uiu, attr, all, Wu, bu)       Bb1 -> Bb0
    gemm_mfma_kernel<<<gGemm, 256, 0, stream>>>(Bb1, Wbu, nullptr, Ab, n);
    fused_agg_kernel<<<gN64, 256, 0, stream>>>(Ab, nullptr, nullptr, ssrc_uiu, attr_uiu_s,
                                               off_uiu, bu, nullptr, Bb0, n);

    // out = cos(u2[src_uiu], u2[dst_uiu])
    rnorm_b16_kernel<<<gN16, 256, 0, stream>>>(Bb0, rnrm, n);
    edge_cos_b16_kernel<<<gE16, 256, 0, stream>>>(Bb0, src_uiu, dst_uiu, rnrm, out, e);
}

// Round 7
// 507.785 us; speedup vs baseline: 2.6607x; 1.1048x over previous
//
#include <hip/hip_runtime.h>
#include <cstdint>
#include <cmath>

#define D 128
#define SCAN_BS 1024

typedef __attribute__((ext_vector_type(8))) short bf16x8;
typedef __attribute__((ext_vector_type(4))) float f32x4;

__device__ __forceinline__ unsigned short f2b(float f) {
    unsigned u = __float_as_uint(f);
    return (unsigned short)((u + 0x7FFFu + ((u >> 16) & 1u)) >> 16);  // RNE
}
__device__ __forceinline__ float b2f(unsigned short u) {
    return __uint_as_float(((unsigned)u) << 16);
}
__device__ __forceinline__ unsigned pack2(float a, float b) {
    return (unsigned)f2b(a) | ((unsigned)f2b(b) << 16);
}
__device__ __forceinline__ float blo(unsigned u) { return __uint_as_float(u << 16); }
__device__ __forceinline__ float bhi(unsigned u) { return __uint_as_float(u & 0xffff0000u); }
__device__ __forceinline__ int swzbyte(int row, int b) {
    return (row << 8) + (b ^ ((row & 7) << 4));   // T2 swizzle, 256B row stride
}

// ---------------------------------------------------------------- mask canon
__global__ void mask_canon_kernel(const unsigned char* __restrict__ mraw,
                                  int* __restrict__ mout, int n) {
    int i = blockIdx.x * blockDim.x + threadIdx.x;
    if (i >= n) return;
    bool isbool = (mraw[1] | mraw[2] | mraw[3]) != 0;
    int v;
    if (isbool) v = (mraw[i] != 0);
    else        v = (((const int*)mraw)[i] != 0);
    mout[i] = v;
}

// ---------------------------------------------------------------- fp32 -> bf16
__global__ void f32_to_b16_kernel(const float* __restrict__ in,
                                  unsigned short* __restrict__ outb, int n8) {
    int t = blockIdx.x * blockDim.x + threadIdx.x;
    if (t >= n8) return;
    const float4* ip = (const float4*)in + (size_t)t * 2;
    float4 a = ip[0], b = ip[1];
    uint4 o;
    o.x = pack2(a.x, a.y); o.y = pack2(a.z, a.w);
    o.z = pack2(b.x, b.y); o.w = pack2(b.z, b.w);
    ((uint4*)outb)[t] = o;
}

// ---------------------------------------------------------------- x-hat
// xnb[i] = bf16( xb[i] / max(||xb[i]||, eps) )   (16 lanes per node)
__global__ void xnorm_b16_kernel(const unsigned short* __restrict__ xb,
                                 unsigned short* __restrict__ xnb, int n) {
    int t = blockIdx.x * blockDim.x + threadIdx.x;
    int i = t >> 4, sl = t & 15;
    if (i >= n) return;
    unsigned rid = ((unsigned)i << 4) | (unsigned)sl;
    uint4 v = ((const uint4*)xb)[rid];
    float f[8];
    float acc = 0.f;
    #pragma unroll
    for (int q = 0; q < 4; q++) {
        unsigned u = (&v.x)[q];
        f[2*q] = blo(u); f[2*q+1] = bhi(u);
        acc += f[2*q]*f[2*q] + f[2*q+1]*f[2*q+1];
    }
    #pragma unroll
    for (int o = 8; o; o >>= 1) acc += __shfl_xor(acc, o);
    float r = 1.0f / fmaxf(sqrtf(acc), 1e-8f);
    uint4 o4;
    #pragma unroll
    for (int q = 0; q < 4; q++) (&o4.x)[q] = pack2(f[2*q] * r, f[2*q+1] * r);
    ((uint4*)xnb)[rid] = o4;
}

// ---------------------------------------------------------------- rnorm (final)
__global__ void rnorm_b16_kernel(const unsigned short* __restrict__ xb,
                                 float* __restrict__ rnrm, int n) {
    int t = blockIdx.x * blockDim.x + threadIdx.x;
    int i = t >> 4, lane = t & 15;
    if (i >= n) return;
    uint4 v = ((const uint4*)(xb + (size_t)i * D))[lane];
    float acc = 0.f;
    #pragma unroll
    for (int q = 0; q < 4; q++) {
        unsigned u = (&v.x)[q];
        float f0 = blo(u), f1 = bhi(u);
        acc += f0 * f0 + f1 * f1;
    }
    #pragma unroll
    for (int o = 8; o; o >>= 1) acc += __shfl_xor(acc, o, 16);
    if (lane == 0) rnrm[i] = 1.0f / fmaxf(sqrtf(acc), 1e-8f);
}

// ---------------------------------------------------------------- counting sort
__global__ void hist_kernel(const int* __restrict__ dst, int* __restrict__ deg, int e_total) {
    int e = blockIdx.x * blockDim.x + threadIdx.x;
    if (e < e_total) atomicAdd(&deg[dst[e]], 1);
}

__global__ __launch_bounds__(SCAN_BS)
void scan_block_kernel(const int* __restrict__ deg, int* __restrict__ off,
                       int* __restrict__ bsum, int n) {
    __shared__ int s[SCAN_BS];
    int gid = blockIdx.x * SCAN_BS + threadIdx.x;
    int v = (gid < n) ? deg[gid] : 0;
    s[threadIdx.x] = v;
    __syncthreads();
    for (int o = 1; o < SCAN_BS; o <<= 1) {
        int t = (threadIdx.x >= o) ? s[threadIdx.x - o] : 0;
        __syncthreads();
        s[threadIdx.x] += t;
        __syncthreads();
    }
    if (gid < n) off[gid] = s[threadIdx.x] - v;
    if (threadIdx.x == SCAN_BS - 1) bsum[blockIdx.x] = s[SCAN_BS - 1];
}

__global__ void scan_bsum_kernel(int* __restrict__ bsum, int nb) {
    __shared__ int s[256];
    int v = (threadIdx.x < nb) ? bsum[threadIdx.x] : 0;
    s[threadIdx.x] = v;
    __syncthreads();
    for (int o = 1; o < 256; o <<= 1) {
        int t = (threadIdx.x >= o) ? s[threadIdx.x - o] : 0;
        __syncthreads();
        s[threadIdx.x] += t;
        __syncthreads();
    }
    if (threadIdx.x < nb) bsum[threadIdx.x] = s[threadIdx.x] - v;
}

__global__ __launch_bounds__(SCAN_BS)
void add_offsets_kernel(int* __restrict__ off, const int* __restrict__ bsum,
                        int* __restrict__ tmp, int n, int e_total) {
    int gid = blockIdx.x * SCAN_BS + threadIdx.x;
    if (gid < n) {
        off[gid] += bsum[blockIdx.x];
        tmp[gid] = 0;
    }
    if (gid == 0) off[n] = e_total;
}

// writes eda[2p] = src (attr half filled by permute_attr_kernel)
__global__ void sort_scatter_kernel(const int* __restrict__ src, const int* __restrict__ dst,
                                    const int* __restrict__ off, int* __restrict__ tmp,
                                    int* __restrict__ eda, int* __restrict__ pos, int e_total) {
    int e = blockIdx.x * blockDim.x + threadIdx.x;
    if (e >= e_total) return;
    int d = dst[e];
    int p = off[d] + atomicAdd(&tmp[d], 1);
    eda[2 * p] = src[e];
    pos[e] = p;
}

__global__ void permute_attr_kernel(const float* __restrict__ a, const int* __restrict__ pos,
                                    int* __restrict__ eda, int e_total) {
    int e = blockIdx.x * blockDim.x + threadIdx.x;
    if (e < e_total) eda[2 * pos[e] + 1] = __float_as_int(a[e]);
}

// ---------------------------------------------------------------- MFMA GEMM
__global__ __launch_bounds__(256)
void gemm_mfma_kernel(const unsigned short* __restrict__ xb,
                      const unsigned short* __restrict__ Wb,
                      const int* __restrict__ mask,
                      unsigned short* __restrict__ hb, int n) {
    __shared__ char sXb[64 * 256];
    __shared__ char sWb[128 * 256];
    const int tid = threadIdx.x;
    const int blockRow0 = blockIdx.x * 64;

    const uint4* xg = (const uint4*)xb + (size_t)blockRow0 * 16;
    #pragma unroll
    for (int it = 0; it < 4; it++) {
        int f = tid + it * 256;
        int row = f >> 4, kc = f & 15;
        uint4 v = make_uint4(0, 0, 0, 0);
        if (blockRow0 + row < n) v = xg[f];
        *(uint4*)(sXb + swzbyte(row, kc * 16)) = v;
    }
    const uint4* wg = (const uint4*)Wb;
    #pragma unroll
    for (int it = 0; it < 8; it++) {
        int f = tid + it * 256;
        int row = f >> 4, kc = f & 15;
        *(uint4*)(sWb + swzbyte(row, kc * 16)) = wg[f];
    }
    __syncthreads();

    const int wid = tid >> 6, lane = tid & 63;
    const int lrow = lane & 15, kg = lane >> 4;
    f32x4 acc[8];
    #pragma unroll
    for (int j = 0; j < 8; j++) acc[j] = (f32x4)(0.f);

    const int arow = wid * 16 + lrow;
    #pragma unroll
    for (int kk = 0; kk < 4; kk++) {
        int kb = kk * 64 + kg * 16;
        bf16x8 af = *(const bf16x8*)(sXb + swzbyte(arow, kb));
        #pragma unroll
        for (int j = 0; j < 8; j++) {
            bf16x8 bfr = *(const bf16x8*)(sWb + swzbyte(j * 16 + lrow, kb));
            acc[j] = __builtin_amdgcn_mfma_f32_16x16x32_bf16(af, bfr, acc[j], 0, 0, 0);
        }
    }

    const int growbase = blockRow0 + wid * 16 + kg * 4;
    const int lrbase = wid * 16 + kg * 4;
    #pragma unroll
    for (int r = 0; r < 4; r++) {
        int row = growbase + r;
        if (row >= n) continue;
        bool pm = mask ? (mask[row] != 0) : true;
        int lr = lrbase + r;
        #pragma unroll
        for (int j = 0; j < 8; j++) {
            int col = j * 16 + lrow;
            unsigned short o;
            if (pm) o = f2b(acc[j][r]);
            else    o = *(const unsigned short*)(sXb + (lr << 8) + ((2 * col) ^ ((lr & 7) << 4)));
            hb[(size_t)row * D + col] = o;
        }
    }
}

// ---------------------------------------------------------------- fused agg
// One 16-lane group per dst node (4 nodes/wave). Lane sl owns cols 8sl..8sl+7
// (one uint4). Edge record eda[p] = {src, attr_bits}. If xnb != null the cos
// weight is fused: c = attr * dot(xhat[s], xhat[i]).
__global__ __launch_bounds__(256)
void fused_agg_kernel(const unsigned short* __restrict__ hb,
                      const unsigned short* __restrict__ xnb,
                      const int* __restrict__ eda,
                      const int* __restrict__ off,
                      const float* __restrict__ bias, const int* __restrict__ mask,
                      unsigned short* __restrict__ outb, int n) {
    int t = blockIdx.x * blockDim.x + threadIdx.x;
    int i = t >> 4, sl = t & 15;
    if (i >= n) return;
    const uint4* h4 = (const uint4*)hb;
    const uint4* x4 = (const uint4*)xnb;
    uint4* o4 = (uint4*)outb;
    unsigned rid = ((unsigned)i << 4) | (unsigned)sl;
    uint4 hv = h4[rid];
    bool m = mask ? (mask[i] != 0) : true;
    if (!m) { o4[rid] = hv; return; }

    float xd[8];
    if (xnb) {
        uint4 xv = x4[rid];
        #pragma unroll
        for (int q = 0; q < 4; q++) {
            unsigned u = (&xv.x)[q];
            xd[2*q] = blo(u); xd[2*q+1] = bhi(u);
        }
    }

    int s0 = off[i], s1 = off[i + 1];
    float acc[8];
    #pragma unroll
    for (int k = 0; k < 8; k++) acc[k] = 0.f;
    const int2* ed2 = (const int2*)eda;

    for (int p = s0; p < s1; ++p) {
        int2 ed = ed2[p];
        unsigned srid = ((unsigned)ed.x << 4) | (unsigned)sl;
        uint4 hs = h4[srid];
        float c = __int_as_float(ed.y);
        if (xnb) {
            uint4 xs = x4[srid];
            float pr = 0.f;
            #pragma unroll
            for (int q = 0; q < 4; q++) {
                unsigned u = (&xs.x)[q];
                pr += blo(u) * xd[2*q] + bhi(u) * xd[2*q+1];
            }
            pr += __shfl_xor(pr, 8);
            pr += __shfl_xor(pr, 4);
            pr += __shfl_xor(pr, 2);
            pr += __shfl_xor(pr, 1);
            c *= pr;
        }
        #pragma unroll
        for (int q = 0; q < 4; q++) {
            unsigned u = (&hs.x)[q];
            acc[2*q]   += c * blo(u);
            acc[2*q+1] += c * bhi(u);
        }
    }

    float inv = 1.0f / fmaxf((float)(s1 - s0), 1.0f);
    const float4* bp = (const float4*)(bias + 8 * sl);
    float4 bv0 = bp[0], bv1 = bp[1];
    float bb[8] = {bv0.x, bv0.y, bv0.z, bv0.w, bv1.x, bv1.y, bv1.z, bv1.w};
    uint4 o;
    #pragma unroll
    for (int q = 0; q < 4; q++) {
        unsigned u = (&hv.x)[q];
        float z0 = acc[2*q]   * inv + blo(u) + bb[2*q];
        float z1 = acc[2*q+1] * inv + bhi(u) + bb[2*q+1];
        float o0 = 1.0f / (1.0f + __expf(-z0));
        float o1 = 1.0f / (1.0f + __expf(-z1));
        (&o.x)[q] = pack2(o0, o1);
    }
    o4[rid] = o;
}

// ---------------------------------------------------------------- final cos
__global__ void edge_cos_b16_kernel(const unsigned short* __restrict__ xb,
                                    const int* __restrict__ src,
                                    const int* __restrict__ dst,
                                    const float* __restrict__ rnrm,
                                    float* __restrict__ out, int e_total) {
    int t = blockIdx.x * blockDim.x + threadIdx.x;
    int e = t >> 4, lane = t & 15;
    if (e >= e_total) return;
    int s = src[e], d = dst[e];
    uint4 a = ((const uint4*)xb)[((unsigned)s << 4) | lane];
    uint4 b = ((const uint4*)xb)[((unsigned)d << 4) | lane];
    float acc = 0.f;
    #pragma unroll
    for (int q = 0; q < 4; q++) {
        unsigned ua = (&a.x)[q], ub = (&b.x)[q];
        acc += blo(ua) * blo(ub) + bhi(ua) * bhi(ub);
    }
    #pragma unroll
    for (int o = 8; o; o >>= 1) acc += __shfl_xor(acc, o, 16);
    if (lane == 0) out[e] = acc * rnrm[s] * rnrm[d];
}

// ---------------------------------------------------------------- host side
static void build_sorted(const int* src, const int* dst, int* off, int* tmp, int* bsum,
                         int* eda, int* pos, int n, int e, hipStream_t stream) {
    int nb = (n + SCAN_BS - 1) / SCAN_BS;
    hipMemsetAsync(tmp, 0, (size_t)n * sizeof(int), stream);
    hist_kernel<<<(e + 255) / 256, 256, 0, stream>>>(dst, tmp, e);
    scan_block_kernel<<<nb, SCAN_BS, 0, stream>>>(tmp, off, bsum, n);
    scan_bsum_kernel<<<1, 256, 0, stream>>>(bsum, nb);
    add_offsets_kernel<<<nb, SCAN_BS, 0, stream>>>(off, bsum, tmp, n, e);
    sort_scatter_kernel<<<(e + 255) / 256, 256, 0, stream>>>(src, dst, off, tmp, eda, pos, e);
}

extern "C" void kernel_launch(void* const* d_in, const int* in_sizes, int n_in,
                              void* d_out, int out_size, void* d_ws, size_t ws_size,
                              hipStream_t stream) {
    const float* x        = (const float*)d_in[0];
    const float* attr_ii  = (const float*)d_in[1];
    const float* attr_uiu = (const float*)d_in[2];
    const float* W1       = (const float*)d_in[3];
    const float* b1       = (const float*)d_in[4];
    const float* W2       = (const float*)d_in[5];
    const float* b2       = (const float*)d_in[6];
    const float* Wu       = (const float*)d_in[7];
    const float* bu       = (const float*)d_in[8];
    const int*   ei_ii    = (const int*)d_in[9];
    const int*   ei_uiu   = (const int*)d_in[10];
    const unsigned char* mraw = (const unsigned char*)d_in[11];

    const int n = in_sizes[0] / D;      // 100000
    const int e = in_sizes[1];          // 600000
    const size_t ND = (size_t)n * D;

    unsigned short* Ab  = (unsigned short*)d_ws;   // h bf16 (per layer)
    unsigned short* Bb0 = Ab + ND;                 // features ping
    unsigned short* Bb1 = Bb0 + ND;                // features pong
    unsigned short* Xn  = Bb1 + ND;                // normalized features
    unsigned short* Wb1 = Xn + ND;
    unsigned short* Wb2 = Wb1 + 16384;
    unsigned short* Wbu = Wb2 + 16384;
    int* eda_ii   = (int*)(Wbu + 16384);           // 2e
    int* eda_uiu  = eda_ii + 2 * (size_t)e;        // 2e
    float* rnrm   = (float*)(eda_uiu + 2 * (size_t)e); // n
    int* maskI    = (int*)(rnrm + n);              // n
    int* tmpA     = maskI + n;                     // n
    int* bsum     = tmpA + n;                      // 256
    int* off_ii   = bsum + 256;                    // n+1
    int* off_uiu  = off_ii + (n + 1);              // n+1
    // transient (preprocessing only): alias into Ab region
    int* pos_ii  = (int*)Ab;                       // e
    int* pos_uiu = pos_ii + e;                     // e

    const int* src_ii  = ei_ii,  * dst_ii  = ei_ii + e;
    const int* src_uiu = ei_uiu, * dst_uiu = ei_uiu + e;
    float* out = (float*)d_out;

    const int gN16 = ((size_t)n * 16 + 255) / 256;
    const int gE16 = ((size_t)e * 16 + 255) / 256;
    const int gGemm = (n + 63) / 64;

    mask_canon_kernel<<<(n + 255) / 256, 256, 0, stream>>>(mraw, maskI, n);

    build_sorted(src_ii,  dst_ii,  off_ii,  tmpA, bsum, eda_ii,  pos_ii,  n, e, stream);
    build_sorted(src_uiu, dst_uiu, off_uiu, tmpA, bsum, eda_uiu, pos_uiu, n, e, stream);
    permute_attr_kernel<<<(e + 255) / 256, 256, 0, stream>>>(attr_ii,  pos_ii,  eda_ii,  e);
    permute_attr_kernel<<<(e + 255) / 256, 256, 0, stream>>>(attr_uiu, pos_uiu, eda_uiu, e);

    f32_to_b16_kernel<<<((int)(ND / 8) + 255) / 256, 256, 0, stream>>>(x, Bb0, (int)(ND / 8));
    f32_to_b16_kernel<<<8, 256, 0, stream>>>(W1, Wb1, 2048);
    f32_to_b16_kernel<<<8, 256, 0, stream>>>(W2, Wb2, 2048);
    f32_to_b16_kernel<<<8, 256, 0, stream>>>(Wu, Wbu, 2048);

    // L1: x1 = cgat(x, ii, cos-fused, mask, W1, b1)   Bb0 -> Bb1
    xnorm_b16_kernel<<<gN16, 256, 0, stream>>>(Bb0, Xn, n);
    gemm_mfma_kernel<<<gGemm, 256, 0, stream>>>(Bb0, Wb1, maskI, Ab, n);
    fused_agg_kernel<<<gN16, 256, 0, stream>>>(Ab, Xn, eda_ii, off_ii, b1, maskI, Bb1, n);

    // L2: x2 = cgat(x1, ii, cos-fused, mask, W2, b2)  Bb1 -> Bb0
    xnorm_b16_kernel<<<gN16, 256, 0, stream>>>(Bb1, Xn, n);
    gemm_mfma_kernel<<<gGemm, 256, 0, stream>>>(Bb1, Wb2, maskI, Ab, n);
    fused_agg_kernel<<<gN16, 256, 0, stream>>>(Ab, Xn, eda_ii, off_ii, b2, maskI, Bb0, n);

    // L3: u1 = cgat(x2, uiu, attr, all, Wu, bu)       Bb0 -> Bb1
    gemm_mfma_kernel<<<gGemm, 256, 0, stream>>>(Bb0, Wbu, nullptr, Ab, n);
    fused_agg_kernel<<<gN16, 256, 0, stream>>>(Ab, nullptr, eda_uiu, off_uiu, bu, nullptr, Bb1, n);

    // L4: u2 = cgat(u1, uiu, attr, all, Wu, bu)       Bb1 -> Bb0
    gemm_mfma_kernel<<<gGemm, 256, 0, stream>>>(Bb1, Wbu, nullptr, Ab, n);
    fused_agg_kernel<<<gN16, 256, 0, stream>>>(Ab, nullptr, eda_uiu, off_uiu, bu, nullptr, Bb0, n);

    // out = cos(u2[src_uiu], u2[dst_uiu])
    rnorm_b16_kernel<<<gN16, 256, 0, stream>>>(Bb0, rnrm, n);
    edge_cos_b16_kernel<<<gE16, 256, 0, stream>>>(Bb0, src_uiu, dst_uiu, rnrm, out, e);
}

// Round 8
// 458.592 us; speedup vs baseline: 2.9461x; 1.1073x over previous
//
#include <hip/hip_runtime.h>
#include <cstdint>
#include <cmath>

#define D 128
#define SCAN_BS 1024

typedef __attribute__((ext_vector_type(8))) short bf16x8;
typedef __attribute__((ext_vector_type(4))) float f32x4;

__device__ __forceinline__ unsigned short f2b(float f) {
    unsigned u = __float_as_uint(f);
    return (unsigned short)((u + 0x7FFFu + ((u >> 16) & 1u)) >> 16);  // RNE
}
__device__ __forceinline__ unsigned pack2(float a, float b) {
    return (unsigned)f2b(a) | ((unsigned)f2b(b) << 16);
}
__device__ __forceinline__ float blo(unsigned u) { return __uint_as_float(u << 16); }
__device__ __forceinline__ float bhi(unsigned u) { return __uint_as_float(u & 0xffff0000u); }
__device__ __forceinline__ int swzbyte(int row, int b) {
    return (row << 8) + (b ^ ((row & 7) << 4));   // T2 swizzle, 256B row stride
}

// ---------------------------------------------------------------- mask canon
__global__ void mask_canon_kernel(const unsigned char* __restrict__ mraw,
                                  int* __restrict__ mout, int n) {
    int i = blockIdx.x * blockDim.x + threadIdx.x;
    if (i >= n) return;
    bool isbool = (mraw[1] | mraw[2] | mraw[3]) != 0;
    int v;
    if (isbool) v = (mraw[i] != 0);
    else        v = (((const int*)mraw)[i] != 0);
    mout[i] = v;
}

// ---------------------------------------------------------------- fp32 -> bf16
__global__ void f32_to_b16_kernel(const float* __restrict__ in,
                                  unsigned short* __restrict__ outb, int n8) {
    int t = blockIdx.x * blockDim.x + threadIdx.x;
    if (t >= n8) return;
    const float4* ip = (const float4*)in + (size_t)t * 2;
    float4 a = ip[0], b = ip[1];
    uint4 o;
    o.x = pack2(a.x, a.y); o.y = pack2(a.z, a.w);
    o.z = pack2(b.x, b.y); o.w = pack2(b.z, b.w);
    ((uint4*)outb)[t] = o;
}

// all three weight matrices in one launch (each 2048 x 8 floats)
__global__ void w3_to_b16_kernel(const float* __restrict__ W1, const float* __restrict__ W2,
                                 const float* __restrict__ Wu,
                                 unsigned short* __restrict__ o1, unsigned short* __restrict__ o2,
                                 unsigned short* __restrict__ ou) {
    int t = blockIdx.x * blockDim.x + threadIdx.x;   // 0..6143
    const float* src; unsigned short* dst; int b;
    if (t < 2048)      { src = W1; dst = o1; b = t; }
    else if (t < 4096) { src = W2; dst = o2; b = t - 2048; }
    else               { src = Wu; dst = ou; b = t - 4096; }
    const float4* ip = (const float4*)src + (size_t)b * 2;
    float4 a = ip[0], c = ip[1];
    uint4 o;
    o.x = pack2(a.x, a.y); o.y = pack2(a.z, a.w);
    o.z = pack2(c.x, c.y); o.w = pack2(c.z, c.w);
    ((uint4*)dst)[b] = o;
}

// ---------------------------------------------------------------- x-hat
__global__ void xnorm_b16_kernel(const unsigned short* __restrict__ xb,
                                 unsigned short* __restrict__ xnb, int n) {
    int t = blockIdx.x * blockDim.x + threadIdx.x;
    int i = t >> 4, sl = t & 15;
    if (i >= n) return;
    unsigned rid = ((unsigned)i << 4) | (unsigned)sl;
    uint4 v = ((const uint4*)xb)[rid];
    float f[8];
    float acc = 0.f;
    #pragma unroll
    for (int q = 0; q < 4; q++) {
        unsigned u = (&v.x)[q];
        f[2*q] = blo(u); f[2*q+1] = bhi(u);
        acc += f[2*q]*f[2*q] + f[2*q+1]*f[2*q+1];
    }
    #pragma unroll
    for (int o = 8; o; o >>= 1) acc += __shfl_xor(acc, o);
    float r = 1.0f / fmaxf(sqrtf(acc), 1e-8f);
    uint4 o4;
    #pragma unroll
    for (int q = 0; q < 4; q++) (&o4.x)[q] = pack2(f[2*q] * r, f[2*q+1] * r);
    ((uint4*)xnb)[rid] = o4;
}

// ---------------------------------------------------------------- rnorm (final)
__global__ void rnorm_b16_kernel(const unsigned short* __restrict__ xb,
                                 float* __restrict__ rnrm, int n) {
    int t = blockIdx.x * blockDim.x + threadIdx.x;
    int i = t >> 4, lane = t & 15;
    if (i >= n) return;
    uint4 v = ((const uint4*)(xb + (size_t)i * D))[lane];
    float acc = 0.f;
    #pragma unroll
    for (int q = 0; q < 4; q++) {
        unsigned u = (&v.x)[q];
        float f0 = blo(u), f1 = bhi(u);
        acc += f0 * f0 + f1 * f1;
    }
    #pragma unroll
    for (int o = 8; o; o >>= 1) acc += __shfl_xor(acc, o, 16);
    if (lane == 0) rnrm[i] = 1.0f / fmaxf(sqrtf(acc), 1e-8f);
}

// ---------------------------------------------------------------- dual-graph counting sort
__global__ void hist2_kernel(const int* __restrict__ dstA, const int* __restrict__ dstB,
                             int* __restrict__ tmp2, int n, int e_total) {
    int t = blockIdx.x * blockDim.x + threadIdx.x;
    if (t < e_total)          atomicAdd(&tmp2[dstA[t]], 1);
    else if (t < 2 * e_total) atomicAdd(&tmp2[n + dstB[t - e_total]], 1);
}

__global__ __launch_bounds__(SCAN_BS)
void scan_block_kernel(const int* __restrict__ deg2, int* __restrict__ off2,
                       int* __restrict__ bsum2, int n) {
    __shared__ int s[SCAN_BS];
    int g = blockIdx.y;
    int gid = blockIdx.x * SCAN_BS + threadIdx.x;
    int v = (gid < n) ? deg2[(size_t)g * n + gid] : 0;
    s[threadIdx.x] = v;
    __syncthreads();
    for (int o = 1; o < SCAN_BS; o <<= 1) {
        int t = (threadIdx.x >= o) ? s[threadIdx.x - o] : 0;
        __syncthreads();
        s[threadIdx.x] += t;
        __syncthreads();
    }
    if (gid < n) off2[(size_t)g * (n + 1) + gid] = s[threadIdx.x] - v;
    if (threadIdx.x == SCAN_BS - 1) bsum2[g * 256 + blockIdx.x] = s[SCAN_BS - 1];
}

__global__ void scan_bsum_kernel(int* __restrict__ bsum2, int nb) {
    __shared__ int s[256];
    int g = blockIdx.y;
    int v = ((int)threadIdx.x < nb) ? bsum2[g * 256 + threadIdx.x] : 0;
    s[threadIdx.x] = v;
    __syncthreads();
    for (int o = 1; o < 256; o <<= 1) {
        int t = (threadIdx.x >= o) ? s[threadIdx.x - o] : 0;
        __syncthreads();
        s[threadIdx.x] += t;
        __syncthreads();
    }
    if ((int)threadIdx.x < nb) bsum2[g * 256 + threadIdx.x] = s[threadIdx.x] - v;
}

__global__ __launch_bounds__(SCAN_BS)
void add_offsets_kernel(int* __restrict__ off2, const int* __restrict__ bsum2,
                        int* __restrict__ tmp2, int n, int e_total) {
    int g = blockIdx.y;
    int gid = blockIdx.x * SCAN_BS + threadIdx.x;
    if (gid < n) {
        off2[(size_t)g * (n + 1) + gid] += bsum2[g * 256 + blockIdx.x];
        tmp2[(size_t)g * n + gid] = 0;
    }
    if (gid == 0) off2[(size_t)g * (n + 1) + n] = e_total;
}

__global__ void sort_scatter2_kernel(const int* __restrict__ srcA, const int* __restrict__ dstA,
                                     const int* __restrict__ srcB, const int* __restrict__ dstB,
                                     const int* __restrict__ off2, int* __restrict__ tmp2,
                                     int* __restrict__ edaA, int* __restrict__ edaB,
                                     int* __restrict__ pos2, int n, int e_total) {
    int t = blockIdx.x * blockDim.x + threadIdx.x;
    if (t >= 2 * e_total) return;
    int g = (t >= e_total);
    int e = t - g * e_total;
    const int* src = g ? srcB : srcA;
    const int* dst = g ? dstB : dstA;
    int* eda = g ? edaB : edaA;
    int d = dst[e];
    int p = off2[(size_t)g * (n + 1) + d] + atomicAdd(&tmp2[(size_t)g * n + d], 1);
    eda[2 * p] = src[e];
    pos2[t] = p;
}

__global__ void permute_attr2_kernel(const float* __restrict__ aA, const float* __restrict__ aB,
                                     const int* __restrict__ pos2,
                                     int* __restrict__ edaA, int* __restrict__ edaB, int e_total) {
    int t = blockIdx.x * blockDim.x + threadIdx.x;
    if (t >= 2 * e_total) return;
    int g = (t >= e_total);
    int e = t - g * e_total;
    const float* a = g ? aB : aA;
    int* eda = g ? edaB : edaA;
    eda[2 * pos2[t] + 1] = __float_as_int(a[e]);
}

// ---------------------------------------------------------------- MFMA GEMM
// 128 rows/block, 512 threads (8 waves x 16 rows). W staged once per 128 rows.
__global__ __launch_bounds__(512)
void gemm_mfma_kernel(const unsigned short* __restrict__ xb,
                      const unsigned short* __restrict__ Wb,
                      const int* __restrict__ mask,
                      unsigned short* __restrict__ hb, int n) {
    __shared__ char sXb[128 * 256];   // 32 KB
    __shared__ char sWb[128 * 256];   // 32 KB
    const int tid = threadIdx.x;
    const int blockRow0 = blockIdx.x * 128;

    const uint4* xg = (const uint4*)xb + (size_t)blockRow0 * 16;
    #pragma unroll
    for (int it = 0; it < 4; it++) {
        int f = tid + it * 512;
        int row = f >> 4, kc = f & 15;
        uint4 v = make_uint4(0, 0, 0, 0);
        if (blockRow0 + row < n) v = xg[f];
        *(uint4*)(sXb + swzbyte(row, kc * 16)) = v;
    }
    const uint4* wg = (const uint4*)Wb;
    #pragma unroll
    for (int it = 0; it < 4; it++) {
        int f = tid + it * 512;
        int row = f >> 4, kc = f & 15;
        *(uint4*)(sWb + swzbyte(row, kc * 16)) = wg[f];
    }
    __syncthreads();

    const int wid = tid >> 6, lane = tid & 63;
    const int lrow = lane & 15, kg = lane >> 4;
    f32x4 acc[8];
    #pragma unroll
    for (int j = 0; j < 8; j++) acc[j] = (f32x4)(0.f);

    const int arow = wid * 16 + lrow;
    #pragma unroll
    for (int kk = 0; kk < 4; kk++) {
        int kb = kk * 64 + kg * 16;
        bf16x8 af = *(const bf16x8*)(sXb + swzbyte(arow, kb));
        #pragma unroll
        for (int j = 0; j < 8; j++) {
            bf16x8 bfr = *(const bf16x8*)(sWb + swzbyte(j * 16 + lrow, kb));
            acc[j] = __builtin_amdgcn_mfma_f32_16x16x32_bf16(af, bfr, acc[j], 0, 0, 0);
        }
    }

    const int growbase = blockRow0 + wid * 16 + kg * 4;
    const int lrbase = wid * 16 + kg * 4;
    #pragma unroll
    for (int r = 0; r < 4; r++) {
        int row = growbase + r;
        if (row >= n) continue;
        bool pm = mask ? (mask[row] != 0) : true;
        int lr = lrbase + r;
        #pragma unroll
        for (int j = 0; j < 8; j++) {
            int col = j * 16 + lrow;
            unsigned short o;
            if (pm) o = f2b(acc[j][r]);
            else    o = *(const unsigned short*)(sXb + (lr << 8) + ((2 * col) ^ ((lr & 7) << 4)));
            hb[(size_t)row * D + col] = o;
        }
    }
}

// ---------------------------------------------------------------- fused agg
// One 16-lane group per dst node. 2x-unrolled edge loop: both edges' row
// gathers issued before either is consumed (doubles memory-level parallelism).
__global__ __launch_bounds__(256)
void fused_agg_kernel(const unsigned short* __restrict__ hb,
                      const unsigned short* __restrict__ xnb,
                      const int* __restrict__ eda,
                      const int* __restrict__ off,
                      const float* __restrict__ bias, const int* __restrict__ mask,
                      unsigned short* __restrict__ outb, int n) {
    int t = blockIdx.x * blockDim.x + threadIdx.x;
    int i = t >> 4, sl = t & 15;
    if (i >= n) return;
    const uint4* h4 = (const uint4*)hb;
    const uint4* x4 = (const uint4*)xnb;
    uint4* o4 = (uint4*)outb;
    unsigned rid = ((unsigned)i << 4) | (unsigned)sl;
    uint4 hv = h4[rid];
    bool m = mask ? (mask[i] != 0) : true;
    if (!m) { o4[rid] = hv; return; }

    float xd[8];
    if (xnb) {
        uint4 xv = x4[rid];
        #pragma unroll
        for (int q = 0; q < 4; q++) {
            unsigned u = (&xv.x)[q];
            xd[2*q] = blo(u); xd[2*q+1] = bhi(u);
        }
    }

    int s0 = off[i], s1 = off[i + 1];
    float acc[8];
    #pragma unroll
    for (int k = 0; k < 8; k++) acc[k] = 0.f;
    const int2* ed2 = (const int2*)eda;

    int p = s0;
    for (; p + 2 <= s1; p += 2) {
        int2 e0 = ed2[p], e1 = ed2[p + 1];
        unsigned r0 = ((unsigned)e0.x << 4) | (unsigned)sl;
        unsigned r1 = ((unsigned)e1.x << 4) | (unsigned)sl;
        uint4 h0 = h4[r0], h1 = h4[r1];
        float c0 = __int_as_float(e0.y), c1 = __int_as_float(e1.y);
        if (xnb) {
            uint4 x0 = x4[r0], x1 = x4[r1];
            float pr0 = 0.f, pr1 = 0.f;
            #pragma unroll
            for (int q = 0; q < 4; q++) {
                unsigned u0 = (&x0.x)[q], u1 = (&x1.x)[q];
                pr0 += blo(u0) * xd[2*q] + bhi(u0) * xd[2*q+1];
                pr1 += blo(u1) * xd[2*q] + bhi(u1) * xd[2*q+1];
            }
            #pragma unroll
            for (int o = 8; o; o >>= 1) {
                pr0 += __shfl_xor(pr0, o);
                pr1 += __shfl_xor(pr1, o);
            }
            c0 *= pr0; c1 *= pr1;
        }
        #pragma unroll
        for (int q = 0; q < 4; q++) {
            unsigned u0 = (&h0.x)[q], u1 = (&h1.x)[q];
            acc[2*q]   += c0 * blo(u0) + c1 * blo(u1);
            acc[2*q+1] += c0 * bhi(u0) + c1 * bhi(u1);
        }
    }
    if (p < s1) {
        int2 e0 = ed2[p];
        unsigned r0 = ((unsigned)e0.x << 4) | (unsigned)sl;
        uint4 h0 = h4[r0];
        float c0 = __int_as_float(e0.y);
        if (xnb) {
            uint4 x0 = x4[r0];
            float pr0 = 0.f;
            #pragma unroll
            for (int q = 0; q < 4; q++) {
                unsigned u0 = (&x0.x)[q];
                pr0 += blo(u0) * xd[2*q] + bhi(u0) * xd[2*q+1];
            }
            #pragma unroll
            for (int o = 8; o; o >>= 1) pr0 += __shfl_xor(pr0, o);
            c0 *= pr0;
        }
        #pragma unroll
        for (int q = 0; q < 4; q++) {
            unsigned u0 = (&h0.x)[q];
            acc[2*q]   += c0 * blo(u0);
            acc[2*q+1] += c0 * bhi(u0);
        }
    }

    float inv = 1.0f / fmaxf((float)(s1 - s0), 1.0f);
    const float4* bp = (const float4*)(bias + 8 * sl);
    float4 bv0 = bp[0], bv1 = bp[1];
    float bb[8] = {bv0.x, bv0.y, bv0.z, bv0.w, bv1.x, bv1.y, bv1.z, bv1.w};
    uint4 o;
    #pragma unroll
    for (int q = 0; q < 4; q++) {
        unsigned u = (&hv.x)[q];
        float z0 = acc[2*q]   * inv + blo(u) + bb[2*q];
        float z1 = acc[2*q+1] * inv + bhi(u) + bb[2*q+1];
        float o0 = 1.0f / (1.0f + __expf(-z0));
        float o1 = 1.0f / (1.0f + __expf(-z1));
        (&o.x)[q] = pack2(o0, o1);
    }
    o4[rid] = o;
}

// ---------------------------------------------------------------- final cos
__global__ void edge_cos_b16_kernel(const unsigned short* __restrict__ xb,
                                    const int* __restrict__ src,
                                    const int* __restrict__ dst,
                                    const float* __restrict__ rnrm,
                                    float* __restrict__ out, int e_total) {
    int t = blockIdx.x * blockDim.x + threadIdx.x;
    int e = t >> 4, lane = t & 15;
    if (e >= e_total) return;
    int s = src[e], d = dst[e];
    uint4 a = ((const uint4*)xb)[((unsigned)s << 4) | lane];
    uint4 b = ((const uint4*)xb)[((unsigned)d << 4) | lane];
    float acc = 0.f;
    #pragma unroll
    for (int q = 0; q < 4; q++) {
        unsigned ua = (&a.x)[q], ub = (&b.x)[q];
        acc += blo(ua) * blo(ub) + bhi(ua) * bhi(ub);
    }
    #pragma unroll
    for (int o = 8; o; o >>= 1) acc += __shfl_xor(acc, o, 16);
    if (lane == 0) out[e] = acc * rnrm[s] * rnrm[d];
}

// ---------------------------------------------------------------- host side
extern "C" void kernel_launch(void* const* d_in, const int* in_sizes, int n_in,
                              void* d_out, int out_size, void* d_ws, size_t ws_size,
                              hipStream_t stream) {
    const float* x        = (const float*)d_in[0];
    const float* attr_ii  = (const float*)d_in[1];
    const float* attr_uiu = (const float*)d_in[2];
    const float* W1       = (const float*)d_in[3];
    const float* b1       = (const float*)d_in[4];
    const float* W2       = (const float*)d_in[5];
    const float* b2       = (const float*)d_in[6];
    const float* Wu       = (const float*)d_in[7];
    const float* bu       = (const float*)d_in[8];
    const int*   ei_ii    = (const int*)d_in[9];
    const int*   ei_uiu   = (const int*)d_in[10];
    const unsigned char* mraw = (const unsigned char*)d_in[11];

    const int n = in_sizes[0] / D;      // 100000
    const int e = in_sizes[1];          // 600000
    const size_t ND = (size_t)n * D;

    unsigned short* Ab  = (unsigned short*)d_ws;   // h bf16 (per layer)
    unsigned short* Bb0 = Ab + ND;                 // features ping
    unsigned short* Bb1 = Bb0 + ND;                // features pong
    unsigned short* Xn  = Bb1 + ND;                // normalized features
    unsigned short* Wb1 = Xn + ND;
    unsigned short* Wb2 = Wb1 + 16384;
    unsigned short* Wbu = Wb2 + 16384;
    int* eda_ii   = (int*)(Wbu + 16384);           // 2e
    int* eda_uiu  = eda_ii + 2 * (size_t)e;        // 2e
    float* rnrm   = (float*)(eda_uiu + 2 * (size_t)e); // n
    int* maskI    = (int*)(rnrm + n);              // n
    int* tmp2     = maskI + n;                     // 2n
    int* bsum2    = tmp2 + 2 * (size_t)n;          // 512
    int* off2     = bsum2 + 512;                   // 2(n+1)
    int* off_ii   = off2;
    int* off_uiu  = off2 + (n + 1);
    // transient (preprocessing only): alias into Ab region (2e ints = 4.8MB < ND ushorts)
    int* pos2     = (int*)Ab;                      // 2e

    const int* src_ii  = ei_ii,  * dst_ii  = ei_ii + e;
    const int* src_uiu = ei_uiu, * dst_uiu = ei_uiu + e;
    float* out = (float*)d_out;

    const int nb = (n + SCAN_BS - 1) / SCAN_BS;
    const int gN16 = ((size_t)n * 16 + 255) / 256;
    const int gE16 = ((size_t)e * 16 + 255) / 256;
    const int gGemm = (n + 127) / 128;

    mask_canon_kernel<<<(n + 255) / 256, 256, 0, stream>>>(mraw, maskI, n);

    // dual-graph counting sort
    hipMemsetAsync(tmp2, 0, 2 * (size_t)n * sizeof(int), stream);
    hist2_kernel<<<(2 * e + 255) / 256, 256, 0, stream>>>(dst_ii, dst_uiu, tmp2, n, e);
    scan_block_kernel<<<dim3(nb, 2), SCAN_BS, 0, stream>>>(tmp2, off2, bsum2, n);
    scan_bsum_kernel<<<dim3(1, 2), 256, 0, stream>>>(bsum2, nb);
    add_offsets_kernel<<<dim3(nb, 2), SCAN_BS, 0, stream>>>(off2, bsum2, tmp2, n, e);
    sort_scatter2_kernel<<<(2 * e + 255) / 256, 256, 0, stream>>>(
        src_ii, dst_ii, src_uiu, dst_uiu, off2, tmp2, eda_ii, eda_uiu, pos2, n, e);
    permute_attr2_kernel<<<(2 * e + 255) / 256, 256, 0, stream>>>(
        attr_ii, attr_uiu, pos2, eda_ii, eda_uiu, e);

    f32_to_b16_kernel<<<((int)(ND / 8) + 255) / 256, 256, 0, stream>>>(x, Bb0, (int)(ND / 8));
    w3_to_b16_kernel<<<24, 256, 0, stream>>>(W1, W2, Wu, Wb1, Wb2, Wbu);

    // L1: x1 = cgat(x, ii, cos-fused, mask, W1, b1)   Bb0 -> Bb1
    xnorm_b16_kernel<<<gN16, 256, 0, stream>>>(Bb0, Xn, n);
    gemm_mfma_kernel<<<gGemm, 512, 0, stream>>>(Bb0, Wb1, maskI, Ab, n);
    fused_agg_kernel<<<gN16, 256, 0, stream>>>(Ab, Xn, eda_ii, off_ii, b1, maskI, Bb1, n);

    // L2: x2 = cgat(x1, ii, cos-fused, mask, W2, b2)  Bb1 -> Bb0
    xnorm_b16_kernel<<<gN16, 256, 0, stream>>>(Bb1, Xn, n);
    gemm_mfma_kernel<<<gGemm, 512, 0, stream>>>(Bb1, Wb2, maskI, Ab, n);
    fused_agg_kernel<<<gN16, 256, 0, stream>>>(Ab, Xn, eda_ii, off_ii, b2, maskI, Bb0, n);

    // L3: u1 = cgat(x2, uiu, attr, all, Wu, bu)       Bb0 -> Bb1
    gemm_mfma_kernel<<<gGemm, 512, 0, stream>>>(Bb0, Wbu, nullptr, Ab, n);
    fused_agg_kernel<<<gN16, 256, 0, stream>>>(Ab, nullptr, eda_uiu, off_uiu, bu, nullptr, Bb1, n);

    // L4: u2 = cgat(u1, uiu, attr, all, Wu, bu)       Bb1 -> Bb0
    gemm_mfma_kernel<<<gGemm, 512, 0, stream>>>(Bb1, Wbu, nullptr, Ab, n);
    fused_agg_kernel<<<gN16, 256, 0, stream>>>(Ab, nullptr, eda_uiu, off_uiu, bu, nullptr, Bb0, n);

    // out = cos(u2[src_uiu], u2[dst_uiu])
    rnorm_b16_kernel<<<gN16, 256, 0, stream>>>(Bb0, rnrm, n);
    edge_cos_b16_kernel<<<gE16, 256, 0, stream>>>(Bb0, src_uiu, dst_uiu, rnrm, out, e);
}

// Round 10
// 378.813 us; speedup vs baseline: 3.5666x; 1.2106x over previous
//
#include <hip/hip_runtime.h>
#include <cstdint>
#include <cmath>

#define D 128
#define SCAN_BS 1024

typedef __attribute__((ext_vector_type(8))) short bf16x8;
typedef __attribute__((ext_vector_type(4))) float f32x4;

__device__ __forceinline__ unsigned short f2b(float f) {
    unsigned u = __float_as_uint(f);
    return (unsigned short)((u + 0x7FFFu + ((u >> 16) & 1u)) >> 16);  // RNE
}
__device__ __forceinline__ unsigned pack2(float a, float b) {
    return (unsigned)f2b(a) | ((unsigned)f2b(b) << 16);
}
__device__ __forceinline__ float blo(unsigned u) { return __uint_as_float(u << 16); }
__device__ __forceinline__ float bhi(unsigned u) { return __uint_as_float(u & 0xffff0000u); }
__device__ __forceinline__ int swzbyte(int row, int b) {
    return (row << 8) + (b ^ ((row & 7) << 4));   // T2 swizzle, 256B row stride
}

// ---------------------------------------------------------------- mask canon
__global__ void mask_canon_kernel(const unsigned char* __restrict__ mraw,
                                  int* __restrict__ mout, int n) {
    int i = blockIdx.x * blockDim.x + threadIdx.x;
    if (i >= n) return;
    bool isbool = (mraw[1] | mraw[2] | mraw[3]) != 0;
    int v;
    if (isbool) v = (mraw[i] != 0);
    else        v = (((const int*)mraw)[i] != 0);
    mout[i] = v;
}

// ---------------------------------------------------------------- conv + xhat
// x fp32 row -> bf16 row (xb) + normalized bf16 row (xnb). 16 lanes/node.
__global__ void conv_norm_kernel(const float* __restrict__ x,
                                 unsigned short* __restrict__ xb,
                                 unsigned short* __restrict__ xnb, int n) {
    int t = blockIdx.x * blockDim.x + threadIdx.x;
    int i = t >> 4, sl = t & 15;
    if (i >= n) return;
    unsigned rid = ((unsigned)i << 4) | (unsigned)sl;
    const float4* ip = (const float4*)(x + (size_t)i * D) + sl * 2;
    float4 a = ip[0], b = ip[1];
    float f[8] = {a.x, a.y, a.z, a.w, b.x, b.y, b.z, b.w};
    float acc = 0.f;
    #pragma unroll
    for (int q = 0; q < 8; q++) acc += f[q] * f[q];
    #pragma unroll
    for (int o = 8; o; o >>= 1) acc += __shfl_xor(acc, o);
    float r = 1.0f / fmaxf(sqrtf(acc), 1e-8f);
    uint4 ob, on;
    #pragma unroll
    for (int q = 0; q < 4; q++) {
        (&ob.x)[q] = pack2(f[2*q], f[2*q+1]);
        (&on.x)[q] = pack2(f[2*q] * r, f[2*q+1] * r);
    }
    ((uint4*)xb)[rid] = ob;
    ((uint4*)xnb)[rid] = on;
}

// all three weight matrices in one launch (each 2048 x 8 floats)
__global__ void w3_to_b16_kernel(const float* __restrict__ W1, const float* __restrict__ W2,
                                 const float* __restrict__ Wu,
                                 unsigned short* __restrict__ o1, unsigned short* __restrict__ o2,
                                 unsigned short* __restrict__ ou) {
    int t = blockIdx.x * blockDim.x + threadIdx.x;   // 0..6143
    const float* src; unsigned short* dst; int b;
    if (t < 2048)      { src = W1; dst = o1; b = t; }
    else if (t < 4096) { src = W2; dst = o2; b = t - 2048; }
    else               { src = Wu; dst = ou; b = t - 4096; }
    const float4* ip = (const float4*)src + (size_t)b * 2;
    float4 a = ip[0], c = ip[1];
    uint4 o;
    o.x = pack2(a.x, a.y); o.y = pack2(a.z, a.w);
    o.z = pack2(c.x, c.y); o.w = pack2(c.z, c.w);
    ((uint4*)dst)[b] = o;
}

// ---------------------------------------------------------------- single-pass sort
// pass 1: rank within destination bucket (the histogram IS the rank)
__global__ void count_pos2_kernel(const int* __restrict__ dstA, const int* __restrict__ dstB,
                                  int* __restrict__ tmp2, int* __restrict__ posw,
                                  int n, int e_total) {
    int t = blockIdx.x * blockDim.x + threadIdx.x;
    if (t >= 2 * e_total) return;
    int g = (t >= e_total);
    int e = t - g * e_total;          // FIX (R9 bug): index within the graph
    int d = (g ? dstB : dstA)[e];
    posw[t] = atomicAdd(&tmp2[(size_t)g * n + d], 1);
}

__global__ __launch_bounds__(SCAN_BS)
void scan_block_kernel(const int* __restrict__ deg2, int* __restrict__ off2,
                       int* __restrict__ bsum2, int n) {
    __shared__ int s[SCAN_BS];
    int g = blockIdx.y;
    int gid = blockIdx.x * SCAN_BS + threadIdx.x;
    int v = (gid < n) ? deg2[(size_t)g * n + gid] : 0;
    s[threadIdx.x] = v;
    __syncthreads();
    for (int o = 1; o < SCAN_BS; o <<= 1) {
        int t = (threadIdx.x >= o) ? s[threadIdx.x - o] : 0;
        __syncthreads();
        s[threadIdx.x] += t;
        __syncthreads();
    }
    if (gid < n) off2[(size_t)g * (n + 1) + gid] = s[threadIdx.x] - v;
    if (threadIdx.x == SCAN_BS - 1) bsum2[g * 256 + blockIdx.x] = s[SCAN_BS - 1];
}

__global__ void scan_bsum_kernel(int* __restrict__ bsum2, int nb) {
    __shared__ int s[256];
    int g = blockIdx.y;
    int v = ((int)threadIdx.x < nb) ? bsum2[g * 256 + threadIdx.x] : 0;
    s[threadIdx.x] = v;
    __syncthreads();
    for (int o = 1; o < 256; o <<= 1) {
        int t = (threadIdx.x >= o) ? s[threadIdx.x - o] : 0;
        __syncthreads();
        s[threadIdx.x] += t;
        __syncthreads();
    }
    if ((int)threadIdx.x < nb) bsum2[g * 256 + threadIdx.x] = s[threadIdx.x] - v;
}

__global__ __launch_bounds__(SCAN_BS)
void add_offsets_kernel(int* __restrict__ off2, const int* __restrict__ bsum2,
                        int n, int e_total) {
    int g = blockIdx.y;
    int gid = blockIdx.x * SCAN_BS + threadIdx.x;
    if (gid < n) off2[(size_t)g * (n + 1) + gid] += bsum2[g * 256 + blockIdx.x];
    if (gid == 0) off2[(size_t)g * (n + 1) + n] = e_total;
}

// pass 2: one int2 {src, attr} store per edge at its final slot
__global__ void scatter_edges2_kernel(const int* __restrict__ srcA, const int* __restrict__ dstA,
                                      const float* __restrict__ aA,
                                      const int* __restrict__ srcB, const int* __restrict__ dstB,
                                      const float* __restrict__ aB,
                                      const int* __restrict__ off2, const int* __restrict__ posw,
                                      int2* __restrict__ edaA, int2* __restrict__ edaB,
                                      int n, int e_total) {
    int t = blockIdx.x * blockDim.x + threadIdx.x;
    if (t >= 2 * e_total) return;
    int g = (t >= e_total);
    int e = t - g * e_total;
    int d = (g ? dstB : dstA)[e];
    int p = off2[(size_t)g * (n + 1) + d] + posw[t];
    int2 rec;
    rec.x = (g ? srcB : srcA)[e];
    rec.y = __float_as_int((g ? aB : aA)[e]);
    (g ? edaB : edaA)[p] = rec;
}

// ---------------------------------------------------------------- MFMA GEMM
__global__ __launch_bounds__(512)
void gemm_mfma_kernel(const unsigned short* __restrict__ xb,
                      const unsigned short* __restrict__ Wb,
                      const int* __restrict__ mask,
                      unsigned short* __restrict__ hb, int n) {
    __shared__ char sXb[128 * 256];   // 32 KB
    __shared__ char sWb[128 * 256];   // 32 KB
    const int tid = threadIdx.x;
    const int blockRow0 = blockIdx.x * 128;

    const uint4* xg = (const uint4*)xb + (size_t)blockRow0 * 16;
    #pragma unroll
    for (int it = 0; it < 4; it++) {
        int f = tid + it * 512;
        int row = f >> 4, kc = f & 15;
        uint4 v = make_uint4(0, 0, 0, 0);
        if (blockRow0 + row < n) v = xg[f];
        *(uint4*)(sXb + swzbyte(row, kc * 16)) = v;
    }
    const uint4* wg = (const uint4*)Wb;
    #pragma unroll
    for (int it = 0; it < 4; it++) {
        int f = tid + it * 512;
        int row = f >> 4, kc = f & 15;
        *(uint4*)(sWb + swzbyte(row, kc * 16)) = wg[f];
    }
    __syncthreads();

    const int wid = tid >> 6, lane = tid & 63;
    const int lrow = lane & 15, kg = lane >> 4;
    f32x4 acc[8];
    #pragma unroll
    for (int j = 0; j < 8; j++) acc[j] = (f32x4)(0.f);

    const int arow = wid * 16 + lrow;
    #pragma unroll
    for (int kk = 0; kk < 4; kk++) {
        int kb = kk * 64 + kg * 16;
        bf16x8 af = *(const bf16x8*)(sXb + swzbyte(arow, kb));
        #pragma unroll
        for (int j = 0; j < 8; j++) {
            bf16x8 bfr = *(const bf16x8*)(sWb + swzbyte(j * 16 + lrow, kb));
            acc[j] = __builtin_amdgcn_mfma_f32_16x16x32_bf16(af, bfr, acc[j], 0, 0, 0);
        }
    }

    const int growbase = blockRow0 + wid * 16 + kg * 4;
    const int lrbase = wid * 16 + kg * 4;
    #pragma unroll
    for (int r = 0; r < 4; r++) {
        int row = growbase + r;
        if (row >= n) continue;
        bool pm = mask ? (mask[row] != 0) : true;
        int lr = lrbase + r;
        #pragma unroll
        for (int j = 0; j < 8; j++) {
            int col = j * 16 + lrow;
            unsigned short o;
            if (pm) o = f2b(acc[j][r]);
            else    o = *(const unsigned short*)(sXb + (lr << 8) + ((2 * col) ^ ((lr & 7) << 4)));
            hb[(size_t)row * D + col] = o;
        }
    }
}

// ---------------------------------------------------------------- fused agg
// One 16-lane group per dst node, 2x-unrolled gather loop. Optionally also
// emits the normalized output row (xnout) for the next layer's fused cos.
__global__ __launch_bounds__(256)
void fused_agg_kernel(const unsigned short* __restrict__ hb,
                      const unsigned short* __restrict__ xnb,
                      const int2* __restrict__ eda,
                      const int* __restrict__ off,
                      const float* __restrict__ bias, const int* __restrict__ mask,
                      unsigned short* __restrict__ outb,
                      unsigned short* __restrict__ xnout, int n) {
    int t = blockIdx.x * blockDim.x + threadIdx.x;
    int i = t >> 4, sl = t & 15;
    if (i >= n) return;
    const uint4* h4 = (const uint4*)hb;
    const uint4* x4 = (const uint4*)xnb;
    uint4* o4 = (uint4*)outb;
    unsigned rid = ((unsigned)i << 4) | (unsigned)sl;
    uint4 hv = h4[rid];
    bool m = mask ? (mask[i] != 0) : true;

    float fo[8];
    if (!m) {
        #pragma unroll
        for (int q = 0; q < 4; q++) {
            unsigned u = (&hv.x)[q];
            fo[2*q] = blo(u); fo[2*q+1] = bhi(u);
        }
    } else {
        float xd[8];
        if (xnb) {
            uint4 xv = x4[rid];
            #pragma unroll
            for (int q = 0; q < 4; q++) {
                unsigned u = (&xv.x)[q];
                xd[2*q] = blo(u); xd[2*q+1] = bhi(u);
            }
        }

        int s0 = off[i], s1 = off[i + 1];
        float acc[8];
        #pragma unroll
        for (int k = 0; k < 8; k++) acc[k] = 0.f;

        int p = s0;
        for (; p + 2 <= s1; p += 2) {
            int2 e0 = eda[p], e1 = eda[p + 1];
            unsigned r0 = ((unsigned)e0.x << 4) | (unsigned)sl;
            unsigned r1 = ((unsigned)e1.x << 4) | (unsigned)sl;
            uint4 h0 = h4[r0], h1 = h4[r1];
            float c0 = __int_as_float(e0.y), c1 = __int_as_float(e1.y);
            if (xnb) {
                uint4 x0 = x4[r0], x1 = x4[r1];
                float pr0 = 0.f, pr1 = 0.f;
                #pragma unroll
                for (int q = 0; q < 4; q++) {
                    unsigned u0 = (&x0.x)[q], u1 = (&x1.x)[q];
                    pr0 += blo(u0) * xd[2*q] + bhi(u0) * xd[2*q+1];
                    pr1 += blo(u1) * xd[2*q] + bhi(u1) * xd[2*q+1];
                }
                #pragma unroll
                for (int o = 8; o; o >>= 1) {
                    pr0 += __shfl_xor(pr0, o);
                    pr1 += __shfl_xor(pr1, o);
                }
                c0 *= pr0; c1 *= pr1;
            }
            #pragma unroll
            for (int q = 0; q < 4; q++) {
                unsigned u0 = (&h0.x)[q], u1 = (&h1.x)[q];
                acc[2*q]   += c0 * blo(u0) + c1 * blo(u1);
                acc[2*q+1] += c0 * bhi(u0) + c1 * bhi(u1);
            }
        }
        if (p < s1) {
            int2 e0 = eda[p];
            unsigned r0 = ((unsigned)e0.x << 4) | (unsigned)sl;
            uint4 h0 = h4[r0];
            float c0 = __int_as_float(e0.y);
            if (xnb) {
                uint4 x0 = x4[r0];
                float pr0 = 0.f;
                #pragma unroll
                for (int q = 0; q < 4; q++) {
                    unsigned u0 = (&x0.x)[q];
                    pr0 += blo(u0) * xd[2*q] + bhi(u0) * xd[2*q+1];
                }
                #pragma unroll
                for (int o = 8; o; o >>= 1) pr0 += __shfl_xor(pr0, o);
                c0 *= pr0;
            }
            #pragma unroll
            for (int q = 0; q < 4; q++) {
                unsigned u0 = (&h0.x)[q];
                acc[2*q]   += c0 * blo(u0);
                acc[2*q+1] += c0 * bhi(u0);
            }
        }

        float inv = 1.0f / fmaxf((float)(s1 - s0), 1.0f);
        const float4* bp = (const float4*)(bias + 8 * sl);
        float4 bv0 = bp[0], bv1 = bp[1];
        float bb[8] = {bv0.x, bv0.y, bv0.z, bv0.w, bv1.x, bv1.y, bv1.z, bv1.w};
        #pragma unroll
        for (int q = 0; q < 4; q++) {
            unsigned u = (&hv.x)[q];
            float z0 = acc[2*q]   * inv + blo(u) + bb[2*q];
            float z1 = acc[2*q+1] * inv + bhi(u) + bb[2*q+1];
            fo[2*q]   = 1.0f / (1.0f + __expf(-z0));
            fo[2*q+1] = 1.0f / (1.0f + __expf(-z1));
        }
    }

    uint4 o;
    #pragma unroll
    for (int q = 0; q < 4; q++) (&o.x)[q] = pack2(fo[2*q], fo[2*q+1]);
    o4[rid] = o;

    if (xnout) {   // emit normalized row for next layer's fused cos
        float ss = 0.f;
        #pragma unroll
        for (int k = 0; k < 8; k++) ss += fo[k] * fo[k];
        #pragma unroll
        for (int o2 = 8; o2; o2 >>= 1) ss += __shfl_xor(ss, o2);
        float r = 1.0f / fmaxf(sqrtf(ss), 1e-8f);
        uint4 on;
        #pragma unroll
        for (int q = 0; q < 4; q++) (&on.x)[q] = pack2(fo[2*q] * r, fo[2*q+1] * r);
        ((uint4*)xnout)[rid] = on;
    }
}

// ---------------------------------------------------------------- final cos
// norms computed inline from the already-gathered rows (no rnrm pass)
__global__ void edge_cos_b16_kernel(const unsigned short* __restrict__ xb,
                                    const int* __restrict__ src,
                                    const int* __restrict__ dst,
                                    float* __restrict__ out, int e_total) {
    int t = blockIdx.x * blockDim.x + threadIdx.x;
    int e = t >> 4, lane = t & 15;
    if (e >= e_total) return;
    int s = src[e], d = dst[e];
    uint4 a = ((const uint4*)xb)[((unsigned)s << 4) | lane];
    uint4 b = ((const uint4*)xb)[((unsigned)d << 4) | lane];
    float sd = 0.f, ss = 0.f, dd = 0.f;
    #pragma unroll
    for (int q = 0; q < 4; q++) {
        unsigned ua = (&a.x)[q], ub = (&b.x)[q];
        float a0 = blo(ua), a1 = bhi(ua), b0 = blo(ub), b1 = bhi(ub);
        sd += a0 * b0 + a1 * b1;
        ss += a0 * a0 + a1 * a1;
        dd += b0 * b0 + b1 * b1;
    }
    #pragma unroll
    for (int o = 8; o; o >>= 1) {
        sd += __shfl_xor(sd, o, 16);
        ss += __shfl_xor(ss, o, 16);
        dd += __shfl_xor(dd, o, 16);
    }
    if (lane == 0) {
        float rs = 1.0f / fmaxf(sqrtf(ss), 1e-8f);
        float rd = 1.0f / fmaxf(sqrtf(dd), 1e-8f);
        out[e] = sd * rs * rd;
    }
}

// ---------------------------------------------------------------- host side
extern "C" void kernel_launch(void* const* d_in, const int* in_sizes, int n_in,
                              void* d_out, int out_size, void* d_ws, size_t ws_size,
                              hipStream_t stream) {
    const float* x        = (const float*)d_in[0];
    const float* attr_ii  = (const float*)d_in[1];
    const float* attr_uiu = (const float*)d_in[2];
    const float* W1       = (const float*)d_in[3];
    const float* b1       = (const float*)d_in[4];
    const float* W2       = (const float*)d_in[5];
    const float* b2       = (const float*)d_in[6];
    const float* Wu       = (const float*)d_in[7];
    const float* bu       = (const float*)d_in[8];
    const int*   ei_ii    = (const int*)d_in[9];
    const int*   ei_uiu   = (const int*)d_in[10];
    const unsigned char* mraw = (const unsigned char*)d_in[11];

    const int n = in_sizes[0] / D;      // 100000
    const int e = in_sizes[1];          // 600000
    const size_t ND = (size_t)n * D;

    unsigned short* Ab  = (unsigned short*)d_ws;   // h bf16 (per layer)
    unsigned short* Bb0 = Ab + ND;                 // features ping
    unsigned short* Bb1 = Bb0 + ND;                // features pong
    unsigned short* Xn0 = Bb1 + ND;                // xhat ping
    unsigned short* Xn1 = Xn0 + ND;                // xhat pong
    unsigned short* Wb1 = Xn1 + ND;
    unsigned short* Wb2 = Wb1 + 16384;
    unsigned short* Wbu = Wb2 + 16384;
    int2* eda_ii  = (int2*)(Wbu + 16384);          // e records
    int2* eda_uiu = eda_ii + e;                    // e records
    int* maskI    = (int*)(eda_uiu + e);           // n
    int* tmp2     = maskI + n;                     // 2n
    int* bsum2    = tmp2 + 2 * (size_t)n;          // 512
    int* off2     = bsum2 + 512;                   // 2(n+1)
    int* off_ii   = off2;
    int* off_uiu  = off2 + (n + 1);
    // transient (preprocessing only): alias into Ab region (2e ints = 4.8MB)
    int* posw     = (int*)Ab;                      // 2e

    const int* src_ii  = ei_ii,  * dst_ii  = ei_ii + e;
    const int* src_uiu = ei_uiu, * dst_uiu = ei_uiu + e;
    float* out = (float*)d_out;

    const int nb = (n + SCAN_BS - 1) / SCAN_BS;
    const int gN16 = ((size_t)n * 16 + 255) / 256;
    const int gE16 = ((size_t)e * 16 + 255) / 256;
    const int gGemm = (n + 127) / 128;

    mask_canon_kernel<<<(n + 255) / 256, 256, 0, stream>>>(mraw, maskI, n);

    // single-atomic-pass dual-graph counting sort
    hipMemsetAsync(tmp2, 0, 2 * (size_t)n * sizeof(int), stream);
    count_pos2_kernel<<<(2 * e + 255) / 256, 256, 0, stream>>>(dst_ii, dst_uiu, tmp2, posw, n, e);
    scan_block_kernel<<<dim3(nb, 2), SCAN_BS, 0, stream>>>(tmp2, off2, bsum2, n);
    scan_bsum_kernel<<<dim3(1, 2), 256, 0, stream>>>(bsum2, nb);
    add_offsets_kernel<<<dim3(nb, 2), SCAN_BS, 0, stream>>>(off2, bsum2, n, e);
    scatter_edges2_kernel<<<(2 * e + 255) / 256, 256, 0, stream>>>(
        src_ii, dst_ii, attr_ii, src_uiu, dst_uiu, attr_uiu, off2, posw, eda_ii, eda_uiu, n, e);

    conv_norm_kernel<<<gN16, 256, 0, stream>>>(x, Bb0, Xn0, n);
    w3_to_b16_kernel<<<24, 256, 0, stream>>>(W1, W2, Wu, Wb1, Wb2, Wbu);

    // L1: x1 = cgat(x, ii, cos-fused, mask, W1, b1)   Bb0 -> Bb1 (+ Xn1)
    gemm_mfma_kernel<<<gGemm, 512, 0, stream>>>(Bb0, Wb1, maskI, Ab, n);
    fused_agg_kernel<<<gN16, 256, 0, stream>>>(Ab, Xn0, eda_ii, off_ii, b1, maskI, Bb1, Xn1, n);

    // L2: x2 = cgat(x1, ii, cos-fused, mask, W2, b2)  Bb1 -> Bb0
    gemm_mfma_kernel<<<gGemm, 512, 0, stream>>>(Bb1, Wb2, maskI, Ab, n);
    fused_agg_kernel<<<gN16, 256, 0, stream>>>(Ab, Xn1, eda_ii, off_ii, b2, maskI, Bb0, nullptr, n);

    // L3: u1 = cgat(x2, uiu, attr, all, Wu, bu)       Bb0 -> Bb1
    gemm_mfma_kernel<<<gGemm, 512, 0, stream>>>(Bb0, Wbu, nullptr, Ab, n);
    fused_agg_kernel<<<gN16, 256, 0, stream>>>(Ab, nullptr, eda_uiu, off_uiu, bu, nullptr, Bb1, nullptr, n);

    // L4: u2 = cgat(u1, uiu, attr, all, Wu, bu)       Bb1 -> Bb0
    gemm_mfma_kernel<<<gGemm, 512, 0, stream>>>(Bb1, Wbu, nullptr, Ab, n);
    fused_agg_kernel<<<gN16, 256, 0, stream>>>(Ab, nullptr, eda_uiu, off_uiu, bu, nullptr, Bb0, nullptr, n);

    // out = cos(u2[src_uiu], u2[dst_uiu])  (norms inline)
    edge_cos_b16_kernel<<<gE16, 256, 0, stream>>>(Bb0, src_uiu, dst_uiu, out, e);
}